// Round 6
// baseline (511.715 us; speedup 1.0000x reference)
//
#include <hip/hip_runtime.h>

// RGCN vulnerability classifier, fp32 in/out, MI355X.
// Y = x @ Wcat as ONE bf16 MFMA GEMM (rs_o folded into epilogue), then atomic-free
// CSR-by-dst gather applying rs_i per (r,d) bucket. CSR built per call (hist+scan+fill).
// deg/hist -> rsqrt -> cast/prep -> scan -> fill -> GEMM1 -> gather1(relu+bias fused)
//   -> GEMM2 -> gather2 -> mean pool -> 32x2 classifier.  Tier-3 fp32 fallback.

#define N_NODES 100000
#define N_REL   8
#define N_EDGES 80000
#define IN_F    128
#define HID     32
#define N_GRAPHS 64
#define NCAT    (N_REL * HID)       // 256
#define N_KEYS  (N_NODES * N_REL)   // 800000
#define TOT_E   (N_REL * N_EDGES)   // 640000

constexpr int TILE = 256;   // tier-3 projection block
constexpr int KC   = 32;

typedef __attribute__((ext_vector_type(8))) short bf16x8;
typedef __attribute__((ext_vector_type(4))) float f32x4;

__device__ __forceinline__ ushort f2bf(float v) {
  unsigned u = __builtin_bit_cast(unsigned, v);
  u = (u + 0x7fffu + ((u >> 16) & 1u)) >> 16;   // RNE
  return (ushort)u;
}
__device__ __forceinline__ float bf2f(ushort h) {
  unsigned u = ((unsigned)h) << 16;
  return __builtin_bit_cast(float, u);
}

// degrees + CSR histogram in one pass over the edge list
__global__ __launch_bounds__(256) void deg_hist_kernel(const int* __restrict__ src, const int* __restrict__ dst,
                                                       int* __restrict__ dego, int* __restrict__ degi,
                                                       int* __restrict__ cnt) {
  int i = blockIdx.x * 256 + threadIdx.x;
  if (i < TOT_E) {
    int r = i / N_EDGES;
    int s = src[i], d = dst[i];
    atomicAdd(&dego[r * N_NODES + s], 1);
    atomicAdd(&degi[r * N_NODES + d], 1);
    atomicAdd(&cnt[d * N_REL + r], 1);
  }
}

__global__ __launch_bounds__(256) void rsqrt_kernel(float* __restrict__ p, int count) {
  int i = blockIdx.x * 256 + threadIdx.x;
  if (i < count) {
    int d = ((const int*)p)[i];
    p[i] = rsqrtf((float)(d < 1 ? 1 : d));
  }
}

__global__ __launch_bounds__(256) void cast_x_kernel(const float* __restrict__ x, ushort* __restrict__ xbf) {
  long i = (blockIdx.x * 256L + threadIdx.x) * 4;
  if (i >= (long)N_NODES * IN_F) return;
  float4 v = *(const float4*)&x[i];
  ushort4 o; o.x = f2bf(v.x); o.y = f2bf(v.y); o.z = f2bf(v.z); o.w = f2bf(v.w);
  *(ushort4*)&xbf[i] = o;
}

// Wt1[n][k] = bf16(W1[r][k][j]), n = r*32+j; Wt2 likewise (B^T layout for MFMA)
__global__ __launch_bounds__(256) void prep_w_kernel(const float* __restrict__ W1, const float* __restrict__ W2,
                                                     ushort* __restrict__ Wt1, ushort* __restrict__ Wt2) {
  int i = blockIdx.x * 256 + threadIdx.x;
  if (i < NCAT * IN_F) {
    int n = i >> 7, k = i & 127;
    int r = n >> 5, j = n & 31;
    Wt1[i] = f2bf(W1[r * (IN_F * HID) + k * HID + j]);
  } else {
    int q = i - NCAT * IN_F;
    if (q < NCAT * HID) {
      int n = q >> 5, k = q & 31;
      int r = n >> 5, j = n & 31;
      Wt2[q] = f2bf(W2[r * (HID * HID) + k * HID + j]);
    }
  }
}

// ---- exclusive scan over cnt[N_KEYS] -> rp, 3-kernel hierarchy (1024 elems/block) ----
__global__ __launch_bounds__(256) void scan1_kernel(const int* __restrict__ in, int* __restrict__ out,
                                                    int* __restrict__ partial, int n) {
  __shared__ int ts[256];
  int b0 = blockIdx.x * 1024;
  int t = threadIdx.x;
  int v[4]; int s = 0;
#pragma unroll
  for (int k = 0; k < 4; k++) {
    int idx = b0 + t * 4 + k;
    v[k] = s;
    s += (idx < n) ? in[idx] : 0;
  }
  ts[t] = s;
  __syncthreads();
  for (int off = 1; off < 256; off <<= 1) {
    int xv = (t >= off) ? ts[t - off] : 0;
    __syncthreads();
    ts[t] += xv;
    __syncthreads();
  }
  int texcl = (t == 0) ? 0 : ts[t - 1];
#pragma unroll
  for (int k = 0; k < 4; k++) {
    int idx = b0 + t * 4 + k;
    if (idx < n) out[idx] = texcl + v[k];
  }
  if (t == 255) partial[blockIdx.x] = ts[255];
}

__global__ __launch_bounds__(256) void scan2_kernel(int* __restrict__ partial, int nb) {
  __shared__ int ts[256];
  int t = threadIdx.x;
  int v[4]; int s = 0;
#pragma unroll
  for (int k = 0; k < 4; k++) {
    int idx = t * 4 + k;
    v[k] = s;
    s += (idx < nb) ? partial[idx] : 0;
  }
  ts[t] = s;
  __syncthreads();
  for (int off = 1; off < 256; off <<= 1) {
    int xv = (t >= off) ? ts[t - off] : 0;
    __syncthreads();
    ts[t] += xv;
    __syncthreads();
  }
  int texcl = (t == 0) ? 0 : ts[t - 1];
#pragma unroll
  for (int k = 0; k < 4; k++) {
    int idx = t * 4 + k;
    if (idx < nb) partial[idx] = texcl + v[k];
  }
}

__global__ __launch_bounds__(256) void scan3_kernel(int* __restrict__ out, const int* __restrict__ partial, int n) {
  int i = blockIdx.x * 256 + threadIdx.x;
  if (i < n) out[i] += partial[i >> 10];
  if (i == 0) out[n] = TOT_E;
}

// CSR fill: col[slot] = src, slots ordered by key = dst*8 + r
__global__ __launch_bounds__(256) void fill_kernel(const int* __restrict__ src, const int* __restrict__ dst,
                                                   const int* __restrict__ rp, int* __restrict__ fillc,
                                                   int* __restrict__ col) {
  int i = blockIdx.x * 256 + threadIdx.x;
  if (i >= TOT_E) return;
  int r = i / N_EDGES;
  int key = dst[i] * N_REL + r;
  int pos = atomicAdd(&fillc[key], 1);
  col[rp[key] + pos] = src[i];
}

// MFMA GEMM: Ys[M x 256] = (A[M x K] @ W[K x 256]) * rs_o[r][m]  (r = col>>5), Y bf16.
// One wave = 16 rows x 256 cols (16 acc tiles). rs_o folded in epilogue (r = nt>>1 is
// tile-constant). Output transposed through LDS (stride 260: write-phase conflict-free)
// then stored as lane-contiguous dwordx4 (1 KB/instruction coalesced).
template<int K>
__global__ __launch_bounds__(256) void gemm_mfma(const ushort* __restrict__ A, const ushort* __restrict__ Bt,
                                                 const float* __restrict__ rs_o, ushort* __restrict__ Y, int M) {
  __shared__ ushort yt[4][16 * 260];
  int wave = threadIdx.x >> 6;
  int lane = threadIdx.x & 63;
  int m0 = (blockIdx.x * 4 + wave) * 16;
  if (m0 >= M) return;
  int row = lane & 15, quad = lane >> 4;
  f32x4 acc[16];
#pragma unroll
  for (int nt = 0; nt < 16; nt++) acc[nt] = (f32x4){0.f, 0.f, 0.f, 0.f};
#pragma unroll
  for (int kq = 0; kq < K / 32; kq++) {
    bf16x8 a = *(const bf16x8*)&A[(size_t)(m0 + row) * K + kq * 32 + quad * 8];
#pragma unroll
    for (int nt = 0; nt < 16; nt++) {
      bf16x8 b = *(const bf16x8*)&Bt[(size_t)(nt * 16 + row) * K + kq * 32 + quad * 8];
      acc[nt] = __builtin_amdgcn_mfma_f32_16x16x32_bf16(a, b, acc[nt], 0, 0, 0);
    }
  }
  // epilogue: scale by rs_o[r][m] (quad-uniform float4 loads), transpose via LDS
  float4 sc[N_REL];
#pragma unroll
  for (int r = 0; r < N_REL; r++)
    sc[r] = *(const float4*)&rs_o[(size_t)r * N_NODES + m0 + quad * 4];
  ushort* myt = &yt[wave][0];
#pragma unroll
  for (int nt = 0; nt < 16; nt++) {
    const float* s4 = (const float*)&sc[nt >> 1];
#pragma unroll
    for (int i = 0; i < 4; i++)
      myt[(quad * 4 + i) * 260 + nt * 16 + row] = f2bf(acc[nt][i] * s4[i]);
  }
  // same-wave LDS RAW -> compiler waitcnt; no barrier needed
  ushort* ybase = &Y[(size_t)m0 * NCAT];
#pragma unroll
  for (int k = 0; k < 8; k++) {
    int g = k * 512 + lane * 8;          // ushort index within the 16x256 tile
    int r2 = g >> 8, c2 = g & 255;
    const ushort* sp = &myt[r2 * 260 + c2];
    uint4 v;
    v.x = *(const uint*)(sp + 0);
    v.y = *(const uint*)(sp + 2);
    v.z = *(const uint*)(sp + 4);
    v.w = *(const uint*)(sp + 6);
    *(uint4*)&ybase[g] = v;              // lanes contiguous -> 1 KB coalesced store
  }
}

// Atomic-free gather, layer 1: H[d][j] = bf16(relu( sum_r rs_i[r][d]*sum_{s in N_r(d)} Ys[s][r*32+j] + sum_r b1[r][j] ))
// One wave per dst node: lane&31 = feature, lane>>5 = 2-way slot parallelism.
__global__ __launch_bounds__(256) void gather1_kernel(const ushort* __restrict__ Ys, const int* __restrict__ col,
                                                      const int* __restrict__ rp, const float* __restrict__ rs_i,
                                                      const float* __restrict__ b1, ushort* __restrict__ H) {
  int wave = threadIdx.x >> 6, lane = threadIdx.x & 63;
  int d = blockIdx.x * 4 + wave;
  if (d >= N_NODES) return;
  int j = lane & 31, half = lane >> 5;
  float sum = 0.f;
#pragma unroll
  for (int r = 0; r < N_REL; r++) {
    int start = rp[d * N_REL + r], end = rp[d * N_REL + r + 1];
    float sub = 0.f;
    for (int t = start + half; t < end; t += 2)
      sub += bf2f(Ys[(size_t)col[t] * NCAT + r * HID + j]);
    sum += rs_i[(size_t)r * N_NODES + d] * sub;
  }
  sum += __shfl_down(sum, 32);
  if (half == 0) {
    float sb = 0.f;
#pragma unroll
    for (int q = 0; q < N_REL; q++) sb += b1[q * HID + j];
    H[(size_t)d * HID + j] = f2bf(fmaxf(sum + sb, 0.f));
  }
}

// layer 2: acc2[d][j] = sum_r rs_i[r][d] * sum Ys (fp32; b2 added in pool)
__global__ __launch_bounds__(256) void gather2_kernel(const ushort* __restrict__ Ys, const int* __restrict__ col,
                                                      const int* __restrict__ rp, const float* __restrict__ rs_i,
                                                      float* __restrict__ acc2) {
  int wave = threadIdx.x >> 6, lane = threadIdx.x & 63;
  int d = blockIdx.x * 4 + wave;
  if (d >= N_NODES) return;
  int j = lane & 31, half = lane >> 5;
  float sum = 0.f;
#pragma unroll
  for (int r = 0; r < N_REL; r++) {
    int start = rp[d * N_REL + r], end = rp[d * N_REL + r + 1];
    float sub = 0.f;
    for (int t = start + half; t < end; t += 2)
      sub += bf2f(Ys[(size_t)col[t] * NCAT + r * HID + j]);
    sum += rs_i[(size_t)r * N_NODES + d] * sub;
  }
  sum += __shfl_down(sum, 32);
  if (half == 0) acc2[(size_t)d * HID + j] = sum;
}

// ---- Tier-3 fp32 fallback kernels (small ws) ----
__global__ __launch_bounds__(256) void deg_kernel(const int* __restrict__ src, const int* __restrict__ dst,
                                                  int* __restrict__ dego, int* __restrict__ degi, int n_rel) {
  int i = blockIdx.x * 256 + threadIdx.x;
  if (i < n_rel * N_EDGES) {
    int r = i / N_EDGES;
    atomicAdd(&dego[r * N_NODES + src[i]], 1);
    atomicAdd(&degi[r * N_NODES + dst[i]], 1);
  }
}

__global__ __launch_bounds__(256) void proj1_kernel(const float* __restrict__ x, const float* __restrict__ W1r0,
                                                    const float* __restrict__ rs_o, float* __restrict__ hw,
                                                    int n0, int n1, int hw_nodes) {
  int rr = blockIdx.y;
  int nb = n0 + blockIdx.x * TILE;
  int t = threadIdx.x;
  __shared__ float xs[TILE][KC + 4];
  const float* __restrict__ Wr = W1r0 + (size_t)rr * (IN_F * HID);
  float acc[HID];
#pragma unroll
  for (int j = 0; j < HID; j++) acc[j] = 0.f;
  for (int kc = 0; kc < IN_F; kc += KC) {
    __syncthreads();
#pragma unroll
    for (int i = 0; i < (TILE * KC / 4) / 256; i++) {
      int q = t + i * 256;
      int nn = q >> 3, k4 = q & 7;
      int n = nb + nn;
      float4 v = make_float4(0.f, 0.f, 0.f, 0.f);
      if (n < n1) v = *(const float4*)&x[(size_t)n * IN_F + kc + k4 * 4];
      *(float4*)&xs[nn][k4 * 4] = v;
    }
    __syncthreads();
#pragma unroll
    for (int k4 = 0; k4 < KC / 4; k4++) {
      float4 xv = *(const float4*)&xs[t][k4 * 4];
      const float* wk = &Wr[(kc + k4 * 4) * HID];
#pragma unroll
      for (int j = 0; j < HID; j++) acc[j] += xv.x * wk[j];
#pragma unroll
      for (int j = 0; j < HID; j++) acc[j] += xv.y * wk[HID + j];
#pragma unroll
      for (int j = 0; j < HID; j++) acc[j] += xv.z * wk[2 * HID + j];
#pragma unroll
      for (int j = 0; j < HID; j++) acc[j] += xv.w * wk[3 * HID + j];
    }
  }
  int n = nb + t;
  if (n < n1) {
    float s = rs_o[(size_t)rr * N_NODES + n];
    float* o = &hw[((size_t)rr * hw_nodes + (n - n0)) * HID];
#pragma unroll
    for (int j4 = 0; j4 < HID / 4; j4++) {
      float4 v = make_float4(acc[j4 * 4] * s, acc[j4 * 4 + 1] * s, acc[j4 * 4 + 2] * s, acc[j4 * 4 + 3] * s);
      *(float4*)&o[j4 * 4] = v;
    }
  }
}

__global__ __launch_bounds__(256) void proj2_kernel(const float* __restrict__ acc1, const float* __restrict__ b1,
                                                    const float* __restrict__ W2r0, const float* __restrict__ rs_o,
                                                    float* __restrict__ hw, int n0, int n1, int hw_nodes) {
  int n = n0 + blockIdx.x * 256 + threadIdx.x;
  if (n >= n1) return;
  int rr = blockIdx.y;
  float h1[HID];
#pragma unroll
  for (int j4 = 0; j4 < HID / 4; j4++) {
    float4 v = *(const float4*)&acc1[(size_t)n * HID + j4 * 4];
    h1[j4 * 4 + 0] = v.x; h1[j4 * 4 + 1] = v.y; h1[j4 * 4 + 2] = v.z; h1[j4 * 4 + 3] = v.w;
  }
#pragma unroll
  for (int j = 0; j < HID; j++) {
    float sb = 0.f;
#pragma unroll
    for (int q = 0; q < N_REL; q++) sb += b1[q * HID + j];
    h1[j] = fmaxf(h1[j] + sb, 0.f);
  }
  const float* __restrict__ Wr = W2r0 + (size_t)rr * (HID * HID);
  float acc[HID];
#pragma unroll
  for (int j = 0; j < HID; j++) acc[j] = 0.f;
#pragma unroll
  for (int k = 0; k < HID; k++) {
    float hv = h1[k];
#pragma unroll
    for (int j = 0; j < HID; j++) acc[j] += hv * Wr[k * HID + j];
  }
  float s = rs_o[(size_t)rr * N_NODES + n];
  float* o = &hw[((size_t)rr * hw_nodes + (n - n0)) * HID];
#pragma unroll
  for (int j4 = 0; j4 < HID / 4; j4++) {
    float4 v = make_float4(acc[j4 * 4] * s, acc[j4 * 4 + 1] * s, acc[j4 * 4 + 2] * s, acc[j4 * 4 + 3] * s);
    *(float4*)&o[j4 * 4] = v;
  }
}

__global__ __launch_bounds__(256) void scatter_kernel(const float* __restrict__ hw, const int* __restrict__ src,
                                                      const int* __restrict__ dst, const float* __restrict__ rs_i,
                                                      float* __restrict__ acc, int nr, int n0, int n1, int hw_nodes) {
  long i = (long)blockIdx.x * 256 + threadIdx.x;
  long total = (long)nr * N_EDGES * HID;
  if (i >= total) return;
  int j = (int)(i & (HID - 1));
  long e = i >> 5;
  int rr = (int)(e / N_EDGES);
  int ee = (int)(e - (long)rr * N_EDGES);
  int s = src[rr * N_EDGES + ee];
  if (s < n0 || s >= n1) return;
  int d = dst[rr * N_EDGES + ee];
  float v = hw[((size_t)rr * hw_nodes + (s - n0)) * HID + j] * rs_i[(size_t)rr * N_NODES + d];
  atomicAdd(&acc[(size_t)d * HID + j], v);
}

// Per-graph sum pool with LDS staging; lane = feature (conflict-free LDS atomics).
__global__ __launch_bounds__(256) void pool_kernel(const float* __restrict__ acc2, const float* __restrict__ b2,
                                                   const int* __restrict__ gid, float* __restrict__ gpool,
                                                   float* __restrict__ gcnt) {
  __shared__ float lp[N_GRAPHS * HID];
  __shared__ float lc[N_GRAPHS];
  int t = threadIdx.x;
  for (int i = t; i < N_GRAPHS * HID; i += 256) lp[i] = 0.f;
  if (t < N_GRAPHS) lc[t] = 0.f;
  __syncthreads();
  int j = t & (HID - 1);
  int grp = t >> 5;
  float sb = 0.f;
#pragma unroll
  for (int q = 0; q < N_REL; q++) sb += b2[q * HID + j];
  for (int n = blockIdx.x * 8 + grp; n < N_NODES; n += gridDim.x * 8) {
    int g = gid[n];
    float v = acc2[(size_t)n * HID + j] + sb;
    atomicAdd(&lp[g * HID + j], v);
    if (j == 0) atomicAdd(&lc[g], 1.f);
  }
  __syncthreads();
  for (int i = t; i < N_GRAPHS * HID; i += 256) atomicAdd(&gpool[i], lp[i]);
  if (t < N_GRAPHS) atomicAdd(&gcnt[t], lc[t]);
}

__global__ void final_kernel(const float* __restrict__ gpool, const float* __restrict__ gcnt,
                             const float* __restrict__ Wc, const float* __restrict__ bc,
                             float* __restrict__ out) {
  int g = threadIdx.x;
  if (g >= N_GRAPHS) return;
  float inv = 1.f / fmaxf(gcnt[g], 1.f);
  float o0 = bc[0], o1 = bc[1];
#pragma unroll
  for (int k = 0; k < HID; k++) {
    float p = gpool[g * HID + k] * inv;
    o0 += p * Wc[k * 2 + 0];
    o1 += p * Wc[k * 2 + 1];
  }
  out[g * 2 + 0] = o0;
  out[g * 2 + 1] = o1;
}

extern "C" void kernel_launch(void* const* d_in, const int* in_sizes, int n_in,
                              void* d_out, int out_size, void* d_ws, size_t ws_size,
                              hipStream_t stream) {
  const float* x  = (const float*)d_in[0];
  const int* src  = (const int*)d_in[1];
  const int* dst  = (const int*)d_in[2];
  const int* gid  = (const int*)d_in[3];
  const float* W1 = (const float*)d_in[5];
  const float* b1 = (const float*)d_in[6];
  const float* W2 = (const float*)d_in[7];
  const float* b2 = (const float*)d_in[8];
  const float* Wc = (const float*)d_in[9];
  const float* bc = (const float*)d_in[10];
  float* out = (float*)d_out;

  float* ws = (float*)d_ws;
  const size_t NF = (size_t)N_NODES * HID;           // 3.2M
  const size_t RN = (size_t)N_REL * N_NODES;         // 800k
  const size_t POOLF = N_GRAPHS * HID + N_GRAPHS;    // 2112
  size_t wsf = ws_size / 4;

  // tier-1 footprint: acc2 + pool + 2*RN + cnt + fill + rp(+pad) + part + col  (floats/ints)
  //                   + (Ys + xbf + Hbf + Wt) ushorts  ~= 28.7M float-slots (~115 MB)
  const size_t T1_NEED = 28900000;

  if (wsf >= T1_NEED) {
    // ---- Tier 1: bf16 MFMA GEMM + CSR gather ----
    float* acc2  = ws;                               // NF (no memset needed: fully written)
    float* gpool = acc2 + NF;                        // zero region starts here
    float* gcnt  = gpool + N_GRAPHS * HID;
    float* rs_o  = gcnt + N_GRAPHS;                  // RN (int degree -> rsqrt in place)
    float* rs_i  = rs_o + RN;                        // RN
    int*   cnt   = (int*)(rs_i + RN);                // N_KEYS
    int*   fillc = cnt + N_KEYS;                     // N_KEYS  -- zero region ends here
    int*   rp    = fillc + N_KEYS;                   // N_KEYS + 4 (pad for alignment)
    int*   part  = rp + N_KEYS + 4;                  // 1024
    int*   colA  = part + 1024;                      // TOT_E
    ushort* Ys   = (ushort*)(colA + TOT_E);          // N*256
    ushort* xbf  = Ys + (size_t)N_NODES * NCAT;      // N*128
    ushort* Hbf  = xbf + (size_t)N_NODES * IN_F;     // N*32
    ushort* Wt1  = Hbf + (size_t)N_NODES * HID;      // 256*128
    ushort* Wt2  = Wt1 + NCAT * IN_F;                // 256*32

    size_t zbytes = (POOLF + 2 * RN + 2 * (size_t)N_KEYS) * 4;   // ~12.8 MB
    hipMemsetAsync(gpool, 0, zbytes, stream);

    deg_hist_kernel<<<(TOT_E + 255) / 256, 256, 0, stream>>>(src, dst, (int*)rs_o, (int*)rs_i, cnt);
    rsqrt_kernel<<<(int)((2 * RN + 255) / 256), 256, 0, stream>>>(rs_o, (int)(2 * RN));
    cast_x_kernel<<<(int)(((size_t)N_NODES * IN_F / 4 + 255) / 256), 256, 0, stream>>>(x, xbf);
    prep_w_kernel<<<(NCAT * IN_F + NCAT * HID + 255) / 256, 256, 0, stream>>>(W1, W2, Wt1, Wt2);

    int sblocks = (N_KEYS + 1023) / 1024;            // 782
    scan1_kernel<<<sblocks, 256, 0, stream>>>(cnt, rp, part, N_KEYS);
    scan2_kernel<<<1, 256, 0, stream>>>(part, sblocks);
    scan3_kernel<<<(N_KEYS + 255) / 256, 256, 0, stream>>>(rp, part, N_KEYS);
    fill_kernel<<<(TOT_E + 255) / 256, 256, 0, stream>>>(src, dst, rp, fillc, colA);

    int gblocks = (N_NODES / 16 + 3) / 4;            // 1563
    int nblocks = (N_NODES + 3) / 4;                 // 25000
    gemm_mfma<IN_F><<<gblocks, 256, 0, stream>>>(xbf, Wt1, rs_o, Ys, N_NODES);
    gather1_kernel<<<nblocks, 256, 0, stream>>>(Ys, colA, rp, rs_i, b1, Hbf);
    gemm_mfma<HID><<<gblocks, 256, 0, stream>>>(Hbf, Wt2, rs_o, Ys, N_NODES);
    gather2_kernel<<<nblocks, 256, 0, stream>>>(Ys, colA, rp, rs_i, acc2);

    pool_kernel<<<256, 256, 0, stream>>>(acc2, b2, gid, gpool, gcnt);
    final_kernel<<<1, 64, 0, stream>>>(gpool, gcnt, Wc, bc, out);
  } else {
    // ---- Tier 3: fp32 per-relation fallback, node-chunked hw ----
    float* acc1  = ws;
    float* acc2  = acc1 + NF;
    float* gpool = acc2 + NF;
    float* gcnt  = gpool + N_GRAPHS * HID;
    float* rsb   = ws + (2 * NF + POOLF);
    size_t zf = 2 * NF + POOLF;
    float* rs_o = rsb;
    float* rs_i = rsb + N_NODES;
    float* hw = rsb + 2 * N_NODES;
    size_t fixed3 = zf + 2 * N_NODES;
    size_t avail = (wsf > fixed3) ? (wsf - fixed3) : 0;
    long chunk = (long)(avail / HID) & ~255L;
    if (chunk < 256) chunk = 256;
    if (chunk > N_NODES) chunk = N_NODES;

    size_t zb = zf * 4; if (zb > ws_size) zb = ws_size;
    hipMemsetAsync(d_ws, 0, zb, stream);

    for (int layer = 0; layer < 2; layer++) {
      for (int r = 0; r < N_REL; r++) {
        hipMemsetAsync(rs_o, 0, 2 * N_NODES * 4, stream);
        deg_kernel<<<(N_EDGES + 255) / 256, 256, 0, stream>>>(src + (size_t)r * N_EDGES, dst + (size_t)r * N_EDGES,
                                                              (int*)rs_o, (int*)rs_i, 1);
        rsqrt_kernel<<<(2 * N_NODES + 255) / 256, 256, 0, stream>>>(rs_o, 2 * N_NODES);
        for (long n0 = 0; n0 < N_NODES; n0 += chunk) {
          long n1 = n0 + chunk; if (n1 > N_NODES) n1 = N_NODES;
          int tiles = (int)((n1 - n0 + TILE - 1) / TILE);
          if (layer == 0)
            proj1_kernel<<<dim3(tiles, 1), 256, 0, stream>>>(x, W1 + (size_t)r * IN_F * HID, rs_o, hw,
                                                             (int)n0, (int)n1, (int)chunk);
          else
            proj2_kernel<<<dim3(tiles, 1), 256, 0, stream>>>(acc1, b1, W2 + (size_t)r * HID * HID, rs_o, hw,
                                                             (int)n0, (int)n1, (int)chunk);
          long tot = (long)N_EDGES * HID;
          scatter_kernel<<<(int)((tot + 255) / 256), 256, 0, stream>>>(hw, src + (size_t)r * N_EDGES,
                                                                       dst + (size_t)r * N_EDGES, rs_i,
                                                                       layer == 0 ? acc1 : acc2,
                                                                       1, (int)n0, (int)n1, (int)chunk);
        }
      }
    }
    pool_kernel<<<256, 256, 0, stream>>>(acc2, b2, gid, gpool, gcnt);
    final_kernel<<<1, 64, 0, stream>>>(gpool, gcnt, Wc, bc, out);
  }
}

// Round 7
// 376.216 us; speedup vs baseline: 1.3602x; 1.3602x over previous
//
#include <hip/hip_runtime.h>

// RGCN vulnerability classifier, fp32 in/out, MI355X.
// Layer1: Y = (x @ Wcat1)*rs_o as ONE bf16 MFMA GEMM; CSR-by-dst gather with MERGED
//   relation buckets (per-slot precomputed offset+weight), fused bias+relu -> H bf16.
// Layer2 collapsed through the linear tail: Vcat = W2_r @ Wc (32x16), Ys2 = H @ Vcat
//   is only [N x 16] fp32; gather2 fused with graph mean-pool; biases folded into a
//   constant in the final kernel.  Tier-3 fp32 fallback for small ws.

#define N_NODES 100000
#define N_REL   8
#define N_EDGES 80000
#define IN_F    128
#define HID     32
#define N_GRAPHS 64
#define NCAT    (N_REL * HID)       // 256
#define N_KEYS  (N_NODES * N_REL)   // 800000
#define TOT_E   (N_REL * N_EDGES)   // 640000

constexpr int TILE = 256;   // tier-3 projection block
constexpr int KC   = 32;

typedef __attribute__((ext_vector_type(8))) short bf16x8;
typedef __attribute__((ext_vector_type(4))) float f32x4;

__device__ __forceinline__ ushort f2bf(float v) {
  unsigned u = __builtin_bit_cast(unsigned, v);
  u = (u + 0x7fffu + ((u >> 16) & 1u)) >> 16;   // RNE
  return (ushort)u;
}
__device__ __forceinline__ float bf2f(ushort h) {
  unsigned u = ((unsigned)h) << 16;
  return __builtin_bit_cast(float, u);
}

// degrees + CSR histogram in one pass
__global__ __launch_bounds__(256) void deg_hist_kernel(const int* __restrict__ src, const int* __restrict__ dst,
                                                       int* __restrict__ dego, int* __restrict__ degi,
                                                       int* __restrict__ cnt) {
  int i = blockIdx.x * 256 + threadIdx.x;
  if (i < TOT_E) {
    int r = i / N_EDGES;
    int s = src[i], d = dst[i];
    atomicAdd(&dego[r * N_NODES + s], 1);
    atomicAdd(&degi[r * N_NODES + d], 1);
    atomicAdd(&cnt[d * N_REL + r], 1);
  }
}

__global__ __launch_bounds__(256) void rsqrt_kernel(float* __restrict__ p, int count) {
  int i = blockIdx.x * 256 + threadIdx.x;
  if (i < count) {
    int d = ((const int*)p)[i];
    p[i] = rsqrtf((float)(d < 1 ? 1 : d));
  }
}

// Wt1[n][k] = bf16(W1[r][k][j]), n=r*32+j (B^T for MFMA).
// Vt[n][k] = bf16( sum_j W2[r][k][j]*Wc[j][c] ), n=r*2+c, k=0..31  (W2@Wc fold).
__global__ __launch_bounds__(256) void prep_w_kernel(const float* __restrict__ W1, const float* __restrict__ W2,
                                                     const float* __restrict__ Wc,
                                                     ushort* __restrict__ Wt1, ushort* __restrict__ Vt) {
  int i = blockIdx.x * 256 + threadIdx.x;
  if (i < NCAT * IN_F) {
    int n = i >> 7, k = i & 127;
    int r = n >> 5, j = n & 31;
    Wt1[i] = f2bf(W1[r * (IN_F * HID) + k * HID + j]);
  } else {
    int q = i - NCAT * IN_F;
    if (q < 16 * HID) {
      int n = q >> 5, k = q & 31;
      int r = n >> 1, c = n & 1;
      float s = 0.f;
#pragma unroll
      for (int j = 0; j < HID; j++) s += W2[r * (HID * HID) + k * HID + j] * Wc[j * 2 + c];
      Vt[q] = f2bf(s);
    }
  }
}

// ---- exclusive scan over cnt[N_KEYS] -> rp ----
__global__ __launch_bounds__(256) void scan1_kernel(const int* __restrict__ in, int* __restrict__ out,
                                                    int* __restrict__ partial, int n) {
  __shared__ int ts[256];
  int b0 = blockIdx.x * 1024;
  int t = threadIdx.x;
  int v[4]; int s = 0;
#pragma unroll
  for (int k = 0; k < 4; k++) {
    int idx = b0 + t * 4 + k;
    v[k] = s;
    s += (idx < n) ? in[idx] : 0;
  }
  ts[t] = s;
  __syncthreads();
  for (int off = 1; off < 256; off <<= 1) {
    int xv = (t >= off) ? ts[t - off] : 0;
    __syncthreads();
    ts[t] += xv;
    __syncthreads();
  }
  int texcl = (t == 0) ? 0 : ts[t - 1];
#pragma unroll
  for (int k = 0; k < 4; k++) {
    int idx = b0 + t * 4 + k;
    if (idx < n) out[idx] = texcl + v[k];
  }
  if (t == 255) partial[blockIdx.x] = ts[255];
}

__global__ __launch_bounds__(256) void scan2_kernel(int* __restrict__ partial, int nb) {
  __shared__ int ts[256];
  int t = threadIdx.x;
  int v[4]; int s = 0;
#pragma unroll
  for (int k = 0; k < 4; k++) {
    int idx = t * 4 + k;
    v[k] = s;
    s += (idx < nb) ? partial[idx] : 0;
  }
  ts[t] = s;
  __syncthreads();
  for (int off = 1; off < 256; off <<= 1) {
    int xv = (t >= off) ? ts[t - off] : 0;
    __syncthreads();
    ts[t] += xv;
    __syncthreads();
  }
  int texcl = (t == 0) ? 0 : ts[t - 1];
#pragma unroll
  for (int k = 0; k < 4; k++) {
    int idx = t * 4 + k;
    if (idx < nb) partial[idx] = texcl + v[k];
  }
}

__global__ __launch_bounds__(256) void scan3_kernel(int* __restrict__ out, const int* __restrict__ partial, int n) {
  int i = blockIdx.x * 256 + threadIdx.x;
  if (i < n) out[i] += partial[i >> 10];
  if (i == 0) out[n] = TOT_E;
}

// CSR fill with per-slot precomputed gather offsets and weight (rs_i[r][d]).
__global__ __launch_bounds__(256) void fill_kernel(const int* __restrict__ src, const int* __restrict__ dst,
                                                   const int* __restrict__ rp, int* __restrict__ fillc,
                                                   const float* __restrict__ rs_i,
                                                   int* __restrict__ ecol1, int* __restrict__ ecol2,
                                                   float* __restrict__ ew) {
  int i = blockIdx.x * 256 + threadIdx.x;
  if (i >= TOT_E) return;
  int r = i / N_EDGES;
  int s = src[i], d = dst[i];
  int key = d * N_REL + r;
  int pos = atomicAdd(&fillc[key], 1);
  int t = rp[key] + pos;
  ecol1[t] = s * NCAT + r * HID;       // ushort index into Ys
  ecol2[t] = s * 16 + r * 2;           // float index into Ys2
  ew[t] = rs_i[(size_t)r * N_NODES + d];
}

// MFMA GEMM layer1: Ys[M x 256] = bf16( (fp32 x @ Wcat) * rs_o[r][m] ), cast fused in A-load.
template<int K>
__global__ __launch_bounds__(256) void gemm_mfma(const float* __restrict__ A, const ushort* __restrict__ Bt,
                                                 const float* __restrict__ rs_o, ushort* __restrict__ Y, int M) {
  __shared__ ushort yt[4][16 * 260];
  int wave = __builtin_amdgcn_readfirstlane(threadIdx.x >> 6);
  int lane = threadIdx.x & 63;
  int m0 = (blockIdx.x * 4 + wave) * 16;
  if (m0 >= M) return;
  int row = lane & 15, quad = lane >> 4;
  f32x4 acc[16];
#pragma unroll
  for (int nt = 0; nt < 16; nt++) acc[nt] = (f32x4){0.f, 0.f, 0.f, 0.f};
#pragma unroll
  for (int kq = 0; kq < K / 32; kq++) {
    const float* ap = &A[(size_t)(m0 + row) * K + kq * 32 + quad * 8];
    float4 a0 = *(const float4*)ap;
    float4 a1 = *(const float4*)(ap + 4);
    bf16x8 a;
    a[0] = (short)f2bf(a0.x); a[1] = (short)f2bf(a0.y); a[2] = (short)f2bf(a0.z); a[3] = (short)f2bf(a0.w);
    a[4] = (short)f2bf(a1.x); a[5] = (short)f2bf(a1.y); a[6] = (short)f2bf(a1.z); a[7] = (short)f2bf(a1.w);
#pragma unroll
    for (int nt = 0; nt < 16; nt++) {
      bf16x8 b = *(const bf16x8*)&Bt[(size_t)(nt * 16 + row) * K + kq * 32 + quad * 8];
      acc[nt] = __builtin_amdgcn_mfma_f32_16x16x32_bf16(a, b, acc[nt], 0, 0, 0);
    }
  }
  float4 sc[N_REL];
#pragma unroll
  for (int r = 0; r < N_REL; r++)
    sc[r] = *(const float4*)&rs_o[(size_t)r * N_NODES + m0 + quad * 4];
  ushort* myt = &yt[wave][0];
#pragma unroll
  for (int nt = 0; nt < 16; nt++) {
    const float* s4 = (const float*)&sc[nt >> 1];
#pragma unroll
    for (int i = 0; i < 4; i++)
      myt[(quad * 4 + i) * 260 + nt * 16 + row] = f2bf(acc[nt][i] * s4[i]);
  }
  ushort* ybase = &Y[(size_t)m0 * NCAT];
#pragma unroll
  for (int k = 0; k < 8; k++) {
    int g = k * 512 + lane * 8;
    int r2 = g >> 8, c2 = g & 255;
    const ushort* sp = &myt[r2 * 260 + c2];
    uint4 v;
    v.x = *(const uint*)(sp + 0);
    v.y = *(const uint*)(sp + 2);
    v.z = *(const uint*)(sp + 4);
    v.w = *(const uint*)(sp + 6);
    *(uint4*)&ybase[g] = v;
  }
}

// MFMA GEMM layer2 (collapsed): Ys2[M x 16] fp32 = (H[M x 32] @ Vcat[32 x 16]) * rs_o[r][m], r = col>>1.
__global__ __launch_bounds__(256) void gemm2_mfma(const ushort* __restrict__ H, const ushort* __restrict__ Vt,
                                                  const float* __restrict__ rs_o, float* __restrict__ Ys2, int M) {
  int wave = __builtin_amdgcn_readfirstlane(threadIdx.x >> 6);
  int lane = threadIdx.x & 63;
  int m0 = (blockIdx.x * 4 + wave) * 16;
  if (m0 >= M) return;
  int row = lane & 15, quad = lane >> 4;
  f32x4 acc = (f32x4){0.f, 0.f, 0.f, 0.f};
  bf16x8 a = *(const bf16x8*)&H[(size_t)(m0 + row) * HID + quad * 8];
  bf16x8 b = *(const bf16x8*)&Vt[row * HID + quad * 8];
  acc = __builtin_amdgcn_mfma_f32_16x16x32_bf16(a, b, acc, 0, 0, 0);
  int r = row >> 1;
#pragma unroll
  for (int i = 0; i < 4; i++) {
    int m = m0 + quad * 4 + i;
    Ys2[(size_t)m * 16 + row] = acc[i] * rs_o[(size_t)r * N_NODES + m];
  }
}

// Gather layer1, merged relation buckets: one wave per dst node; lane&31 = feature,
// lane>>5 = 2-way slot parallelism over the node's contiguous slot range.
__global__ __launch_bounds__(256) void gather1_kernel(const ushort* __restrict__ Ys, const int* __restrict__ ecol1,
                                                      const float* __restrict__ ew, const int* __restrict__ rp,
                                                      const float* __restrict__ b1, ushort* __restrict__ H) {
  int wave = __builtin_amdgcn_readfirstlane(threadIdx.x >> 6);
  int lane = threadIdx.x & 63;
  int d = blockIdx.x * 4 + wave;
  if (d >= N_NODES) return;
  int j = lane & 31, half = lane >> 5;
  int base = rp[d * N_REL], endp = rp[d * N_REL + N_REL];
  float sum = 0.f;
  for (int t = base + half; t < endp; t += 2) {
    int off = ecol1[t];
    float w = ew[t];
    sum += w * bf2f(Ys[(size_t)off + j]);
  }
  sum += __shfl_down(sum, 32);
  if (half == 0) {
    float sb = 0.f;
#pragma unroll
    for (int q = 0; q < N_REL; q++) sb += b1[q * HID + j];
    H[(size_t)d * HID + j] = f2bf(fmaxf(sum + sb, 0.f));
  }
}

// Gather layer2 fused with per-graph pooling: thread per node computes z[d] (2 floats),
// accumulates into LDS per-graph pool, block-flushes with global atomics.
__global__ __launch_bounds__(256) void gather2_pool_kernel(const float* __restrict__ Ys2,
                                                           const int* __restrict__ ecol2,
                                                           const float* __restrict__ ew, const int* __restrict__ rp,
                                                           const int* __restrict__ gid,
                                                           float* __restrict__ gpool, float* __restrict__ gcnt) {
  __shared__ float lp[N_GRAPHS * 2];
  __shared__ float lc[N_GRAPHS];
  int t = threadIdx.x;
  if (t < N_GRAPHS * 2) lp[t] = 0.f;
  if (t < N_GRAPHS) lc[t] = 0.f;
  __syncthreads();
  for (int n = blockIdx.x * 256 + t; n < N_NODES; n += gridDim.x * 256) {
    int base = rp[n * N_REL], endp = rp[n * N_REL + N_REL];
    float z0 = 0.f, z1 = 0.f;
    for (int s = base; s < endp; s++) {
      float w = ew[s];
      float2 y = *(const float2*)&Ys2[ecol2[s]];
      z0 += w * y.x;
      z1 += w * y.y;
    }
    int g = gid[n];
    atomicAdd(&lp[g * 2 + 0], z0);
    atomicAdd(&lp[g * 2 + 1], z1);
    atomicAdd(&lc[g], 1.f);
  }
  __syncthreads();
  if (t < N_GRAPHS * 2) atomicAdd(&gpool[t], lp[t]);
  if (t < N_GRAPHS) atomicAdd(&gcnt[t], lc[t]);
}

// out[g] = gpool[g]/cnt + (sum_r b2[r]) @ Wc + bc   (cnt==0 -> bc exactly)
__global__ void final_kernel(const float* __restrict__ gpool, const float* __restrict__ gcnt,
                             const float* __restrict__ b2, const float* __restrict__ Wc,
                             const float* __restrict__ bc, float* __restrict__ out) {
  int g = threadIdx.x;
  if (g >= N_GRAPHS) return;
  float c0 = 0.f, c1 = 0.f;
#pragma unroll
  for (int k = 0; k < HID; k++) {
    float sb = 0.f;
#pragma unroll
    for (int r = 0; r < N_REL; r++) sb += b2[r * HID + k];
    c0 += sb * Wc[k * 2 + 0];
    c1 += sb * Wc[k * 2 + 1];
  }
  float cntv = gcnt[g];
  if (cntv > 0.f) {
    out[g * 2 + 0] = gpool[g * 2 + 0] / cntv + c0 + bc[0];
    out[g * 2 + 1] = gpool[g * 2 + 1] / cntv + c1 + bc[1];
  } else {
    out[g * 2 + 0] = bc[0];
    out[g * 2 + 1] = bc[1];
  }
}

// ---- Tier-3 fp32 fallback kernels (small ws) ----
__global__ __launch_bounds__(256) void deg_kernel(const int* __restrict__ src, const int* __restrict__ dst,
                                                  int* __restrict__ dego, int* __restrict__ degi, int n_rel) {
  int i = blockIdx.x * 256 + threadIdx.x;
  if (i < n_rel * N_EDGES) {
    int r = i / N_EDGES;
    atomicAdd(&dego[r * N_NODES + src[i]], 1);
    atomicAdd(&degi[r * N_NODES + dst[i]], 1);
  }
}

__global__ __launch_bounds__(256) void proj1_kernel(const float* __restrict__ x, const float* __restrict__ W1r0,
                                                    const float* __restrict__ rs_o, float* __restrict__ hw,
                                                    int n0, int n1, int hw_nodes) {
  int rr = blockIdx.y;
  int nb = n0 + blockIdx.x * TILE;
  int t = threadIdx.x;
  __shared__ float xs[TILE][KC + 4];
  const float* __restrict__ Wr = W1r0 + (size_t)rr * (IN_F * HID);
  float acc[HID];
#pragma unroll
  for (int j = 0; j < HID; j++) acc[j] = 0.f;
  for (int kc = 0; kc < IN_F; kc += KC) {
    __syncthreads();
#pragma unroll
    for (int i = 0; i < (TILE * KC / 4) / 256; i++) {
      int q = t + i * 256;
      int nn = q >> 3, k4 = q & 7;
      int n = nb + nn;
      float4 v = make_float4(0.f, 0.f, 0.f, 0.f);
      if (n < n1) v = *(const float4*)&x[(size_t)n * IN_F + kc + k4 * 4];
      *(float4*)&xs[nn][k4 * 4] = v;
    }
    __syncthreads();
#pragma unroll
    for (int k4 = 0; k4 < KC / 4; k4++) {
      float4 xv = *(const float4*)&xs[t][k4 * 4];
      const float* wk = &Wr[(kc + k4 * 4) * HID];
#pragma unroll
      for (int j = 0; j < HID; j++) acc[j] += xv.x * wk[j];
#pragma unroll
      for (int j = 0; j < HID; j++) acc[j] += xv.y * wk[HID + j];
#pragma unroll
      for (int j = 0; j < HID; j++) acc[j] += xv.z * wk[2 * HID + j];
#pragma unroll
      for (int j = 0; j < HID; j++) acc[j] += xv.w * wk[3 * HID + j];
    }
  }
  int n = nb + t;
  if (n < n1) {
    float s = rs_o[(size_t)rr * N_NODES + n];
    float* o = &hw[((size_t)rr * hw_nodes + (n - n0)) * HID];
#pragma unroll
    for (int j4 = 0; j4 < HID / 4; j4++) {
      float4 v = make_float4(acc[j4 * 4] * s, acc[j4 * 4 + 1] * s, acc[j4 * 4 + 2] * s, acc[j4 * 4 + 3] * s);
      *(float4*)&o[j4 * 4] = v;
    }
  }
}

__global__ __launch_bounds__(256) void proj2_kernel(const float* __restrict__ acc1, const float* __restrict__ b1,
                                                    const float* __restrict__ W2r0, const float* __restrict__ rs_o,
                                                    float* __restrict__ hw, int n0, int n1, int hw_nodes) {
  int n = n0 + blockIdx.x * 256 + threadIdx.x;
  if (n >= n1) return;
  int rr = blockIdx.y;
  float h1[HID];
#pragma unroll
  for (int j4 = 0; j4 < HID / 4; j4++) {
    float4 v = *(const float4*)&acc1[(size_t)n * HID + j4 * 4];
    h1[j4 * 4 + 0] = v.x; h1[j4 * 4 + 1] = v.y; h1[j4 * 4 + 2] = v.z; h1[j4 * 4 + 3] = v.w;
  }
#pragma unroll
  for (int j = 0; j < HID; j++) {
    float sb = 0.f;
#pragma unroll
    for (int q = 0; q < N_REL; q++) sb += b1[q * HID + j];
    h1[j] = fmaxf(h1[j] + sb, 0.f);
  }
  const float* __restrict__ Wr = W2r0 + (size_t)rr * (HID * HID);
  float acc[HID];
#pragma unroll
  for (int j = 0; j < HID; j++) acc[j] = 0.f;
#pragma unroll
  for (int k = 0; k < HID; k++) {
    float hv = h1[k];
#pragma unroll
    for (int j = 0; j < HID; j++) acc[j] += hv * Wr[k * HID + j];
  }
  float s = rs_o[(size_t)rr * N_NODES + n];
  float* o = &hw[((size_t)rr * hw_nodes + (n - n0)) * HID];
#pragma unroll
  for (int j4 = 0; j4 < HID / 4; j4++) {
    float4 v = make_float4(acc[j4 * 4] * s, acc[j4 * 4 + 1] * s, acc[j4 * 4 + 2] * s, acc[j4 * 4 + 3] * s);
    *(float4*)&o[j4 * 4] = v;
  }
}

__global__ __launch_bounds__(256) void scatter_kernel(const float* __restrict__ hw, const int* __restrict__ src,
                                                      const int* __restrict__ dst, const float* __restrict__ rs_i,
                                                      float* __restrict__ acc, int nr, int n0, int n1, int hw_nodes) {
  long i = (long)blockIdx.x * 256 + threadIdx.x;
  long total = (long)nr * N_EDGES * HID;
  if (i >= total) return;
  int j = (int)(i & (HID - 1));
  long e = i >> 5;
  int rr = (int)(e / N_EDGES);
  int ee = (int)(e - (long)rr * N_EDGES);
  int s = src[rr * N_EDGES + ee];
  if (s < n0 || s >= n1) return;
  int d = dst[rr * N_EDGES + ee];
  float v = hw[((size_t)rr * hw_nodes + (s - n0)) * HID + j] * rs_i[(size_t)rr * N_NODES + d];
  atomicAdd(&acc[(size_t)d * HID + j], v);
}

__global__ __launch_bounds__(256) void pool_kernel(const float* __restrict__ acc2, const float* __restrict__ b2,
                                                   const int* __restrict__ gid, float* __restrict__ gpool,
                                                   float* __restrict__ gcnt) {
  __shared__ float lp[N_GRAPHS * HID];
  __shared__ float lc[N_GRAPHS];
  int t = threadIdx.x;
  for (int i = t; i < N_GRAPHS * HID; i += 256) lp[i] = 0.f;
  if (t < N_GRAPHS) lc[t] = 0.f;
  __syncthreads();
  int j = t & (HID - 1);
  int grp = t >> 5;
  float sb = 0.f;
#pragma unroll
  for (int q = 0; q < N_REL; q++) sb += b2[q * HID + j];
  for (int n = blockIdx.x * 8 + grp; n < N_NODES; n += gridDim.x * 8) {
    int g = gid[n];
    float v = acc2[(size_t)n * HID + j] + sb;
    atomicAdd(&lp[g * HID + j], v);
    if (j == 0) atomicAdd(&lc[g], 1.f);
  }
  __syncthreads();
  for (int i = t; i < N_GRAPHS * HID; i += 256) atomicAdd(&gpool[i], lp[i]);
  if (t < N_GRAPHS) atomicAdd(&gcnt[t], lc[t]);
}

__global__ void final3_kernel(const float* __restrict__ gpool, const float* __restrict__ gcnt,
                              const float* __restrict__ Wc, const float* __restrict__ bc,
                              float* __restrict__ out) {
  int g = threadIdx.x;
  if (g >= N_GRAPHS) return;
  float inv = 1.f / fmaxf(gcnt[g], 1.f);
  float o0 = bc[0], o1 = bc[1];
#pragma unroll
  for (int k = 0; k < HID; k++) {
    float p = gpool[g * HID + k] * inv;
    o0 += p * Wc[k * 2 + 0];
    o1 += p * Wc[k * 2 + 1];
  }
  out[g * 2 + 0] = o0;
  out[g * 2 + 1] = o1;
}

extern "C" void kernel_launch(void* const* d_in, const int* in_sizes, int n_in,
                              void* d_out, int out_size, void* d_ws, size_t ws_size,
                              hipStream_t stream) {
  const float* x  = (const float*)d_in[0];
  const int* src  = (const int*)d_in[1];
  const int* dst  = (const int*)d_in[2];
  const int* gid  = (const int*)d_in[3];
  const float* W1 = (const float*)d_in[5];
  const float* b1 = (const float*)d_in[6];
  const float* W2 = (const float*)d_in[7];
  const float* b2 = (const float*)d_in[8];
  const float* Wc = (const float*)d_in[9];
  const float* bc = (const float*)d_in[10];
  float* out = (float*)d_out;

  float* ws = (float*)d_ws;
  const size_t NF = (size_t)N_NODES * HID;           // 3.2M
  const size_t RN = (size_t)N_REL * N_NODES;         // 800k
  const size_t POOLF = N_GRAPHS * HID + N_GRAPHS;
  size_t wsf = ws_size / 4;

  const size_t T1_NEED = 22500000;   // ~90 MB (layout below sums to ~21.9M float slots)

  if (wsf >= T1_NEED) {
    // ---- Tier 1 ----
    float* gpool = ws;                               // 128  (zero region start)
    float* gcnt  = gpool + N_GRAPHS * 2;             // 64
    float* rs_o  = gcnt + N_GRAPHS;                  // RN
    float* rs_i  = rs_o + RN;                        // RN
    int*   cnt   = (int*)(rs_i + RN);                // N_KEYS
    int*   fillc = cnt + N_KEYS;                     // N_KEYS (zero region end)
    int*   rp    = fillc + N_KEYS;                   // N_KEYS + 8
    int*   part  = rp + N_KEYS + 8;                  // 1024
    int*   ecol1 = part + 1024;                      // TOT_E
    int*   ecol2 = ecol1 + TOT_E;                    // TOT_E
    float* ew    = (float*)(ecol2 + TOT_E);          // TOT_E
    float* Ys2   = ew + TOT_E;                       // N*16 fp32 (even offset -> float2 ok)
    ushort* Ys   = (ushort*)(Ys2 + (size_t)N_NODES * 16);    // N*256
    ushort* Hbf  = Ys + (size_t)N_NODES * NCAT;              // N*32
    ushort* Wt1  = Hbf + (size_t)N_NODES * HID;              // 256*128
    ushort* Vt   = Wt1 + NCAT * IN_F;                        // 16*32

    size_t zbytes = (N_GRAPHS * 3 + 2 * RN + 2 * (size_t)N_KEYS) * 4;   // ~12.8 MB
    hipMemsetAsync(ws, 0, zbytes, stream);

    deg_hist_kernel<<<(TOT_E + 255) / 256, 256, 0, stream>>>(src, dst, (int*)rs_o, (int*)rs_i, cnt);
    rsqrt_kernel<<<(int)((2 * RN + 255) / 256), 256, 0, stream>>>(rs_o, (int)(2 * RN));
    prep_w_kernel<<<(NCAT * IN_F + 16 * HID + 255) / 256, 256, 0, stream>>>(W1, W2, Wc, Wt1, Vt);

    int sblocks = (N_KEYS + 1023) / 1024;
    scan1_kernel<<<sblocks, 256, 0, stream>>>(cnt, rp, part, N_KEYS);
    scan2_kernel<<<1, 256, 0, stream>>>(part, sblocks);
    scan3_kernel<<<(N_KEYS + 255) / 256, 256, 0, stream>>>(rp, part, N_KEYS);
    fill_kernel<<<(TOT_E + 255) / 256, 256, 0, stream>>>(src, dst, rp, fillc, rs_i, ecol1, ecol2, ew);

    int gblocks = (N_NODES / 16 + 3) / 4;
    int nblocks = (N_NODES + 3) / 4;
    gemm_mfma<IN_F><<<gblocks, 256, 0, stream>>>(x, Wt1, rs_o, Ys, N_NODES);
    gather1_kernel<<<nblocks, 256, 0, stream>>>(Ys, ecol1, ew, rp, b1, Hbf);
    gemm2_mfma<<<gblocks, 256, 0, stream>>>(Hbf, Vt, rs_o, Ys2, N_NODES);
    gather2_pool_kernel<<<416, 256, 0, stream>>>(Ys2, ecol2, ew, rp, gid, gpool, gcnt);
    final_kernel<<<1, 64, 0, stream>>>(gpool, gcnt, b2, Wc, bc, out);
  } else {
    // ---- Tier 3: fp32 per-relation fallback, node-chunked hw ----
    float* acc1  = ws;
    float* acc2  = acc1 + NF;
    float* gpool = acc2 + NF;
    float* gcnt  = gpool + N_GRAPHS * HID;
    float* rsb   = ws + (2 * NF + POOLF);
    size_t zf = 2 * NF + POOLF;
    float* rs_o = rsb;
    float* rs_i = rsb + N_NODES;
    float* hw = rsb + 2 * N_NODES;
    size_t fixed3 = zf + 2 * N_NODES;
    size_t avail = (wsf > fixed3) ? (wsf - fixed3) : 0;
    long chunk = (long)(avail / HID) & ~255L;
    if (chunk < 256) chunk = 256;
    if (chunk > N_NODES) chunk = N_NODES;

    size_t zb = zf * 4; if (zb > ws_size) zb = ws_size;
    hipMemsetAsync(d_ws, 0, zb, stream);

    for (int layer = 0; layer < 2; layer++) {
      for (int r = 0; r < N_REL; r++) {
        hipMemsetAsync(rs_o, 0, 2 * N_NODES * 4, stream);
        deg_kernel<<<(N_EDGES + 255) / 256, 256, 0, stream>>>(src + (size_t)r * N_EDGES, dst + (size_t)r * N_EDGES,
                                                              (int*)rs_o, (int*)rs_i, 1);
        rsqrt_kernel<<<(2 * N_NODES + 255) / 256, 256, 0, stream>>>(rs_o, 2 * N_NODES);
        for (long n0 = 0; n0 < N_NODES; n0 += chunk) {
          long n1 = n0 + chunk; if (n1 > N_NODES) n1 = N_NODES;
          int tiles = (int)((n1 - n0 + TILE - 1) / TILE);
          if (layer == 0)
            proj1_kernel<<<dim3(tiles, 1), 256, 0, stream>>>(x, W1 + (size_t)r * IN_F * HID, rs_o, hw,
                                                             (int)n0, (int)n1, (int)chunk);
          else
            proj2_kernel<<<dim3(tiles, 1), 256, 0, stream>>>(acc1, b1, W2 + (size_t)r * HID * HID, rs_o, hw,
                                                             (int)n0, (int)n1, (int)chunk);
          long tot = (long)N_EDGES * HID;
          scatter_kernel<<<(int)((tot + 255) / 256), 256, 0, stream>>>(hw, src + (size_t)r * N_EDGES,
                                                                       dst + (size_t)r * N_EDGES, rs_i,
                                                                       layer == 0 ? acc1 : acc2,
                                                                       1, (int)n0, (int)n1, (int)chunk);
        }
      }
    }
    pool_kernel<<<256, 256, 0, stream>>>(acc2, b2, gid, gpool, gcnt);
    final3_kernel<<<1, 64, 0, stream>>>(gpool, gcnt, Wc, bc, out);
  }
}

// Round 9
// 363.927 us; speedup vs baseline: 1.4061x; 1.0338x over previous
//
#include <hip/hip_runtime.h>

// RGCN vulnerability classifier, fp32 in/out, MI355X.
// == Round-7 passing pipeline ==  (Y = x@Wcat bf16 MFMA with rs_o epilogue; CSR-by-dst
// gather, merged relation buckets, ew=rs_i; layer2 collapsed via Vcat=W2@Wc; gather2
// fused with pooling)  + ONE change: deg_hist and fill are XCD-partitioned (team
// q=blockIdx&7 re-reads all edges, updates only its 1/8 node range) so atomic counter
// lines stay XCD-local. Outputs of both kernels are bitwise-identical to round 7.
// Tier-3 fp32 fallback for small ws.

#define N_NODES 100000
#define N_REL   8
#define N_EDGES 80000
#define IN_F    128
#define HID     32
#define N_GRAPHS 64
#define NCAT    (N_REL * HID)       // 256
#define N_KEYS  (N_NODES * N_REL)   // 800000
#define TOT_E   (N_REL * N_EDGES)   // 640000
#define DRANGE  12500               // N_NODES / 8 teams

constexpr int TILE = 256;   // tier-3 projection block
constexpr int KC   = 32;

typedef __attribute__((ext_vector_type(8))) short bf16x8;
typedef __attribute__((ext_vector_type(4))) float f32x4;

__device__ __forceinline__ ushort f2bf(float v) {
  unsigned u = __builtin_bit_cast(unsigned, v);
  u = (u + 0x7fffu + ((u >> 16) & 1u)) >> 16;   // RNE
  return (ushort)u;
}
__device__ __forceinline__ float bf2f(ushort h) {
  unsigned u = ((unsigned)h) << 16;
  return __builtin_bit_cast(float, u);
}

// degrees + CSR histogram, XCD-partitioned: team q owns node range [q*DRANGE,(q+1)*DRANGE).
// dego keyed by s-ownership; degi/cnt by d-ownership. Counts identical to round 7.
__global__ __launch_bounds__(256) void deg_hist_kernel(const int* __restrict__ src, const int* __restrict__ dst,
                                                       int* __restrict__ dego, int* __restrict__ degi,
                                                       int* __restrict__ cnt) {
  int q = blockIdx.x & 7;
  int bb = blockIdx.x >> 3;
  int nb = gridDim.x >> 3;
  for (int i = bb * 256 + threadIdx.x; i < TOT_E; i += nb * 256) {
    int s = src[i], d = dst[i];
    int r = i / N_EDGES;
    if (s / DRANGE == q) atomicAdd(&dego[r * N_NODES + s], 1);
    if (d / DRANGE == q) {
      atomicAdd(&degi[r * N_NODES + d], 1);
      atomicAdd(&cnt[d * N_REL + r], 1);
    }
  }
}

__global__ __launch_bounds__(256) void rsqrt_kernel(float* __restrict__ p, int count) {
  int i = blockIdx.x * 256 + threadIdx.x;
  if (i < count) {
    int d = ((const int*)p)[i];
    p[i] = rsqrtf((float)(d < 1 ? 1 : d));
  }
}

// Wt1[n][k] = bf16(W1[r][k][j]), n=r*32+j (B^T for MFMA).
// Vt[n][k] = bf16( sum_j W2[r][k][j]*Wc[j][c] ), n=r*2+c (W2@Wc fold).
__global__ __launch_bounds__(256) void prep_w_kernel(const float* __restrict__ W1, const float* __restrict__ W2,
                                                     const float* __restrict__ Wc,
                                                     ushort* __restrict__ Wt1, ushort* __restrict__ Vt) {
  int i = blockIdx.x * 256 + threadIdx.x;
  if (i < NCAT * IN_F) {
    int n = i >> 7, k = i & 127;
    int r = n >> 5, j = n & 31;
    Wt1[i] = f2bf(W1[r * (IN_F * HID) + k * HID + j]);
  } else {
    int q = i - NCAT * IN_F;
    if (q < 16 * HID) {
      int n = q >> 5, k = q & 31;
      int r = n >> 1, c = n & 1;
      float s = 0.f;
#pragma unroll
      for (int j = 0; j < HID; j++) s += W2[r * (HID * HID) + k * HID + j] * Wc[j * 2 + c];
      Vt[q] = f2bf(s);
    }
  }
}

// ---- exclusive scan over cnt[N_KEYS] -> rp ----
__global__ __launch_bounds__(256) void scan1_kernel(const int* __restrict__ in, int* __restrict__ out,
                                                    int* __restrict__ partial, int n) {
  __shared__ int ts[256];
  int b0 = blockIdx.x * 1024;
  int t = threadIdx.x;
  int v[4]; int s = 0;
#pragma unroll
  for (int k = 0; k < 4; k++) {
    int idx = b0 + t * 4 + k;
    v[k] = s;
    s += (idx < n) ? in[idx] : 0;
  }
  ts[t] = s;
  __syncthreads();
  for (int off = 1; off < 256; off <<= 1) {
    int xv = (t >= off) ? ts[t - off] : 0;
    __syncthreads();
    ts[t] += xv;
    __syncthreads();
  }
  int texcl = (t == 0) ? 0 : ts[t - 1];
#pragma unroll
  for (int k = 0; k < 4; k++) {
    int idx = b0 + t * 4 + k;
    if (idx < n) out[idx] = texcl + v[k];
  }
  if (t == 255) partial[blockIdx.x] = ts[255];
}

__global__ __launch_bounds__(256) void scan2_kernel(int* __restrict__ partial, int nb) {
  __shared__ int ts[256];
  int t = threadIdx.x;
  int v[4]; int s = 0;
#pragma unroll
  for (int k = 0; k < 4; k++) {
    int idx = t * 4 + k;
    v[k] = s;
    s += (idx < nb) ? partial[idx] : 0;
  }
  ts[t] = s;
  __syncthreads();
  for (int off = 1; off < 256; off <<= 1) {
    int xv = (t >= off) ? ts[t - off] : 0;
    __syncthreads();
    ts[t] += xv;
    __syncthreads();
  }
  int texcl = (t == 0) ? 0 : ts[t - 1];
#pragma unroll
  for (int k = 0; k < 4; k++) {
    int idx = t * 4 + k;
    if (idx < nb) partial[idx] = texcl + v[k];
  }
}

__global__ __launch_bounds__(256) void scan3_kernel(int* __restrict__ out, const int* __restrict__ partial, int n) {
  int i = blockIdx.x * 256 + threadIdx.x;
  if (i < n) out[i] += partial[i >> 10];
  if (i == 0) out[n] = TOT_E;
}

// CSR fill, XCD-partitioned by d-ownership; output identical to round 7's fill.
__global__ __launch_bounds__(256) void fill_kernel(const int* __restrict__ src, const int* __restrict__ dst,
                                                   const int* __restrict__ rp, int* __restrict__ fillc,
                                                   const float* __restrict__ rs_i,
                                                   int* __restrict__ ecol1, int* __restrict__ ecol2,
                                                   float* __restrict__ ew) {
  int q = blockIdx.x & 7;
  int bb = blockIdx.x >> 3;
  int nb = gridDim.x >> 3;
  for (int i = bb * 256 + threadIdx.x; i < TOT_E; i += nb * 256) {
    int d = dst[i];
    if (d / DRANGE != q) continue;
    int s = src[i];
    int r = i / N_EDGES;
    int key = d * N_REL + r;
    int pos = atomicAdd(&fillc[key], 1);
    int t = rp[key] + pos;
    ecol1[t] = s * NCAT + r * HID;       // ushort index into Ys
    ecol2[t] = s * 16 + r * 2;           // float index into Ys2
    ew[t] = rs_i[(size_t)r * N_NODES + d];
  }
}

// MFMA GEMM layer1: Ys[M x 256] = bf16( (fp32 x @ Wcat) * rs_o[r][m] ), cast fused in A-load.
template<int K>
__global__ __launch_bounds__(256) void gemm_mfma(const float* __restrict__ A, const ushort* __restrict__ Bt,
                                                 const float* __restrict__ rs_o, ushort* __restrict__ Y, int M) {
  __shared__ ushort yt[4][16 * 260];
  int wave = __builtin_amdgcn_readfirstlane(threadIdx.x >> 6);
  int lane = threadIdx.x & 63;
  int m0 = (blockIdx.x * 4 + wave) * 16;
  if (m0 >= M) return;
  int row = lane & 15, quad = lane >> 4;
  f32x4 acc[16];
#pragma unroll
  for (int nt = 0; nt < 16; nt++) acc[nt] = (f32x4){0.f, 0.f, 0.f, 0.f};
#pragma unroll
  for (int kq = 0; kq < K / 32; kq++) {
    const float* ap = &A[(size_t)(m0 + row) * K + kq * 32 + quad * 8];
    float4 a0 = *(const float4*)ap;
    float4 a1 = *(const float4*)(ap + 4);
    bf16x8 a;
    a[0] = (short)f2bf(a0.x); a[1] = (short)f2bf(a0.y); a[2] = (short)f2bf(a0.z); a[3] = (short)f2bf(a0.w);
    a[4] = (short)f2bf(a1.x); a[5] = (short)f2bf(a1.y); a[6] = (short)f2bf(a1.z); a[7] = (short)f2bf(a1.w);
#pragma unroll
    for (int nt = 0; nt < 16; nt++) {
      bf16x8 b = *(const bf16x8*)&Bt[(size_t)(nt * 16 + row) * K + kq * 32 + quad * 8];
      acc[nt] = __builtin_amdgcn_mfma_f32_16x16x32_bf16(a, b, acc[nt], 0, 0, 0);
    }
  }
  float4 sc[N_REL];
#pragma unroll
  for (int r = 0; r < N_REL; r++)
    sc[r] = *(const float4*)&rs_o[(size_t)r * N_NODES + m0 + quad * 4];
  ushort* myt = &yt[wave][0];
#pragma unroll
  for (int nt = 0; nt < 16; nt++) {
    const float* s4 = (const float*)&sc[nt >> 1];
#pragma unroll
    for (int i = 0; i < 4; i++)
      myt[(quad * 4 + i) * 260 + nt * 16 + row] = f2bf(acc[nt][i] * s4[i]);
  }
  ushort* ybase = &Y[(size_t)m0 * NCAT];
#pragma unroll
  for (int k = 0; k < 8; k++) {
    int g = k * 512 + lane * 8;
    int r2 = g >> 8, c2 = g & 255;
    const ushort* sp = &myt[r2 * 260 + c2];
    uint4 v;
    v.x = *(const uint*)(sp + 0);
    v.y = *(const uint*)(sp + 2);
    v.z = *(const uint*)(sp + 4);
    v.w = *(const uint*)(sp + 6);
    *(uint4*)&ybase[g] = v;
  }
}

// MFMA GEMM layer2 (collapsed): Ys2[M x 16] fp32 = (H[M x 32] @ Vcat[32 x 16]) * rs_o[r][m], r = col>>1.
__global__ __launch_bounds__(256) void gemm2_mfma(const ushort* __restrict__ H, const ushort* __restrict__ Vt,
                                                  const float* __restrict__ rs_o, float* __restrict__ Ys2, int M) {
  int wave = __builtin_amdgcn_readfirstlane(threadIdx.x >> 6);
  int lane = threadIdx.x & 63;
  int m0 = (blockIdx.x * 4 + wave) * 16;
  if (m0 >= M) return;
  int row = lane & 15, quad = lane >> 4;
  f32x4 acc = (f32x4){0.f, 0.f, 0.f, 0.f};
  bf16x8 a = *(const bf16x8*)&H[(size_t)(m0 + row) * HID + quad * 8];
  bf16x8 b = *(const bf16x8*)&Vt[row * HID + quad * 8];
  acc = __builtin_amdgcn_mfma_f32_16x16x32_bf16(a, b, acc, 0, 0, 0);
  int r = row >> 1;
#pragma unroll
  for (int i = 0; i < 4; i++) {
    int m = m0 + quad * 4 + i;
    Ys2[(size_t)m * 16 + row] = acc[i] * rs_o[(size_t)r * N_NODES + m];
  }
}

// Gather layer1, merged relation buckets: one wave per dst node; lane&31 = feature,
// lane>>5 = 2-way slot parallelism over the node's contiguous slot range.
__global__ __launch_bounds__(256) void gather1_kernel(const ushort* __restrict__ Ys, const int* __restrict__ ecol1,
                                                      const float* __restrict__ ew, const int* __restrict__ rp,
                                                      const float* __restrict__ b1, ushort* __restrict__ H) {
  int wave = __builtin_amdgcn_readfirstlane(threadIdx.x >> 6);
  int lane = threadIdx.x & 63;
  int d = blockIdx.x * 4 + wave;
  if (d >= N_NODES) return;
  int j = lane & 31, half = lane >> 5;
  int base = rp[d * N_REL], endp = rp[d * N_REL + N_REL];
  float sum = 0.f;
  for (int t = base + half; t < endp; t += 2) {
    int off = ecol1[t];
    float w = ew[t];
    sum += w * bf2f(Ys[(size_t)off + j]);
  }
  sum += __shfl_down(sum, 32);
  if (half == 0) {
    float sb = 0.f;
#pragma unroll
    for (int q = 0; q < N_REL; q++) sb += b1[q * HID + j];
    H[(size_t)d * HID + j] = f2bf(fmaxf(sum + sb, 0.f));
  }
}

// Gather layer2 fused with per-graph pooling.
__global__ __launch_bounds__(256) void gather2_pool_kernel(const float* __restrict__ Ys2,
                                                           const int* __restrict__ ecol2,
                                                           const float* __restrict__ ew, const int* __restrict__ rp,
                                                           const int* __restrict__ gid,
                                                           float* __restrict__ gpool, float* __restrict__ gcnt) {
  __shared__ float lp[N_GRAPHS * 2];
  __shared__ float lc[N_GRAPHS];
  int t = threadIdx.x;
  if (t < N_GRAPHS * 2) lp[t] = 0.f;
  if (t < N_GRAPHS) lc[t] = 0.f;
  __syncthreads();
  for (int n = blockIdx.x * 256 + t; n < N_NODES; n += gridDim.x * 256) {
    int base = rp[n * N_REL], endp = rp[n * N_REL + N_REL];
    float z0 = 0.f, z1 = 0.f;
    for (int s = base; s < endp; s++) {
      float w = ew[s];
      float2 y = *(const float2*)&Ys2[ecol2[s]];
      z0 += w * y.x;
      z1 += w * y.y;
    }
    int g = gid[n];
    atomicAdd(&lp[g * 2 + 0], z0);
    atomicAdd(&lp[g * 2 + 1], z1);
    atomicAdd(&lc[g], 1.f);
  }
  __syncthreads();
  if (t < N_GRAPHS * 2) atomicAdd(&gpool[t], lp[t]);
  if (t < N_GRAPHS) atomicAdd(&gcnt[t], lc[t]);
}

// out[g] = gpool[g]/cnt + (sum_r b2[r]) @ Wc + bc   (cnt==0 -> bc exactly)
__global__ void final_kernel(const float* __restrict__ gpool, const float* __restrict__ gcnt,
                             const float* __restrict__ b2, const float* __restrict__ Wc,
                             const float* __restrict__ bc, float* __restrict__ out) {
  int g = threadIdx.x;
  if (g >= N_GRAPHS) return;
  float c0 = 0.f, c1 = 0.f;
#pragma unroll
  for (int k = 0; k < HID; k++) {
    float sb = 0.f;
#pragma unroll
    for (int r = 0; r < N_REL; r++) sb += b2[r * HID + k];
    c0 += sb * Wc[k * 2 + 0];
    c1 += sb * Wc[k * 2 + 1];
  }
  float cntv = gcnt[g];
  if (cntv > 0.f) {
    out[g * 2 + 0] = gpool[g * 2 + 0] / cntv + c0 + bc[0];
    out[g * 2 + 1] = gpool[g * 2 + 1] / cntv + c1 + bc[1];
  } else {
    out[g * 2 + 0] = bc[0];
    out[g * 2 + 1] = bc[1];
  }
}

// ---- Tier-3 fp32 fallback kernels (small ws) ----
__global__ __launch_bounds__(256) void deg_kernel(const int* __restrict__ src, const int* __restrict__ dst,
                                                  int* __restrict__ dego, int* __restrict__ degi, int n_rel) {
  int i = blockIdx.x * 256 + threadIdx.x;
  if (i < n_rel * N_EDGES) {
    int r = i / N_EDGES;
    atomicAdd(&dego[r * N_NODES + src[i]], 1);
    atomicAdd(&degi[r * N_NODES + dst[i]], 1);
  }
}

__global__ __launch_bounds__(256) void proj1_kernel(const float* __restrict__ x, const float* __restrict__ W1r0,
                                                    const float* __restrict__ rs_o, float* __restrict__ hw,
                                                    int n0, int n1, int hw_nodes) {
  int rr = blockIdx.y;
  int nb = n0 + blockIdx.x * TILE;
  int t = threadIdx.x;
  __shared__ float xs[TILE][KC + 4];
  const float* __restrict__ Wr = W1r0 + (size_t)rr * (IN_F * HID);
  float acc[HID];
#pragma unroll
  for (int j = 0; j < HID; j++) acc[j] = 0.f;
  for (int kc = 0; kc < IN_F; kc += KC) {
    __syncthreads();
#pragma unroll
    for (int i = 0; i < (TILE * KC / 4) / 256; i++) {
      int q = t + i * 256;
      int nn = q >> 3, k4 = q & 7;
      int n = nb + nn;
      float4 v = make_float4(0.f, 0.f, 0.f, 0.f);
      if (n < n1) v = *(const float4*)&x[(size_t)n * IN_F + kc + k4 * 4];
      *(float4*)&xs[nn][k4 * 4] = v;
    }
    __syncthreads();
#pragma unroll
    for (int k4 = 0; k4 < KC / 4; k4++) {
      float4 xv = *(const float4*)&xs[t][k4 * 4];
      const float* wk = &Wr[(kc + k4 * 4) * HID];
#pragma unroll
      for (int j = 0; j < HID; j++) acc[j] += xv.x * wk[j];
#pragma unroll
      for (int j = 0; j < HID; j++) acc[j] += xv.y * wk[HID + j];
#pragma unroll
      for (int j = 0; j < HID; j++) acc[j] += xv.z * wk[2 * HID + j];
#pragma unroll
      for (int j = 0; j < HID; j++) acc[j] += xv.w * wk[3 * HID + j];
    }
  }
  int n = nb + t;
  if (n < n1) {
    float s = rs_o[(size_t)rr * N_NODES + n];
    float* o = &hw[((size_t)rr * hw_nodes + (n - n0)) * HID];
#pragma unroll
    for (int j4 = 0; j4 < HID / 4; j4++) {
      float4 v = make_float4(acc[j4 * 4] * s, acc[j4 * 4 + 1] * s, acc[j4 * 4 + 2] * s, acc[j4 * 4 + 3] * s);
      *(float4*)&o[j4 * 4] = v;
    }
  }
}

__global__ __launch_bounds__(256) void proj2_kernel(const float* __restrict__ acc1, const float* __restrict__ b1,
                                                    const float* __restrict__ W2r0, const float* __restrict__ rs_o,
                                                    float* __restrict__ hw, int n0, int n1, int hw_nodes) {
  int n = n0 + blockIdx.x * 256 + threadIdx.x;
  if (n >= n1) return;
  int rr = blockIdx.y;
  float h1[HID];
#pragma unroll
  for (int j4 = 0; j4 < HID / 4; j4++) {
    float4 v = *(const float4*)&acc1[(size_t)n * HID + j4 * 4];
    h1[j4 * 4 + 0] = v.x; h1[j4 * 4 + 1] = v.y; h1[j4 * 4 + 2] = v.z; h1[j4 * 4 + 3] = v.w;
  }
#pragma unroll
  for (int j = 0; j < HID; j++) {
    float sb = 0.f;
#pragma unroll
    for (int q = 0; q < N_REL; q++) sb += b1[q * HID + j];
    h1[j] = fmaxf(h1[j] + sb, 0.f);
  }
  const float* __restrict__ Wr = W2r0 + (size_t)rr * (HID * HID);
  float acc[HID];
#pragma unroll
  for (int j = 0; j < HID; j++) acc[j] = 0.f;
#pragma unroll
  for (int k = 0; k < HID; k++) {
    float hv = h1[k];
#pragma unroll
    for (int j = 0; j < HID; j++) acc[j] += hv * Wr[k * HID + j];
  }
  float s = rs_o[(size_t)rr * N_NODES + n];
  float* o = &hw[((size_t)rr * hw_nodes + (n - n0)) * HID];
#pragma unroll
  for (int j4 = 0; j4 < HID / 4; j4++) {
    float4 v = make_float4(acc[j4 * 4] * s, acc[j4 * 4 + 1] * s, acc[j4 * 4 + 2] * s, acc[j4 * 4 + 3] * s);
    *(float4*)&o[j4 * 4] = v;
  }
}

__global__ __launch_bounds__(256) void scatter_kernel(const float* __restrict__ hw, const int* __restrict__ src,
                                                      const int* __restrict__ dst, const float* __restrict__ rs_i,
                                                      float* __restrict__ acc, int nr, int n0, int n1, int hw_nodes) {
  long i = (long)blockIdx.x * 256 + threadIdx.x;
  long total = (long)nr * N_EDGES * HID;
  if (i >= total) return;
  int j = (int)(i & (HID - 1));
  long e = i >> 5;
  int rr = (int)(e / N_EDGES);
  int ee = (int)(e - (long)rr * N_EDGES);
  int s = src[rr * N_EDGES + ee];
  if (s < n0 || s >= n1) return;
  int d = dst[rr * N_EDGES + ee];
  float v = hw[((size_t)rr * hw_nodes + (s - n0)) * HID + j] * rs_i[(size_t)rr * N_NODES + d];
  atomicAdd(&acc[(size_t)d * HID + j], v);
}

__global__ __launch_bounds__(256) void pool_kernel(const float* __restrict__ acc2, const float* __restrict__ b2,
                                                   const int* __restrict__ gid, float* __restrict__ gpool,
                                                   float* __restrict__ gcnt) {
  __shared__ float lp[N_GRAPHS * HID];
  __shared__ float lc[N_GRAPHS];
  int t = threadIdx.x;
  for (int i = t; i < N_GRAPHS * HID; i += 256) lp[i] = 0.f;
  if (t < N_GRAPHS) lc[t] = 0.f;
  __syncthreads();
  int j = t & (HID - 1);
  int grp = t >> 5;
  float sb = 0.f;
#pragma unroll
  for (int q = 0; q < N_REL; q++) sb += b2[q * HID + j];
  for (int n = blockIdx.x * 8 + grp; n < N_NODES; n += gridDim.x * 8) {
    int g = gid[n];
    float v = acc2[(size_t)n * HID + j] + sb;
    atomicAdd(&lp[g * HID + j], v);
    if (j == 0) atomicAdd(&lc[g], 1.f);
  }
  __syncthreads();
  for (int i = t; i < N_GRAPHS * HID; i += 256) atomicAdd(&gpool[i], lp[i]);
  if (t < N_GRAPHS) atomicAdd(&gcnt[t], lc[t]);
}

__global__ void final3_kernel(const float* __restrict__ gpool, const float* __restrict__ gcnt,
                              const float* __restrict__ Wc, const float* __restrict__ bc,
                              float* __restrict__ out) {
  int g = threadIdx.x;
  if (g >= N_GRAPHS) return;
  float inv = 1.f / fmaxf(gcnt[g], 1.f);
  float o0 = bc[0], o1 = bc[1];
#pragma unroll
  for (int k = 0; k < HID; k++) {
    float p = gpool[g * HID + k] * inv;
    o0 += p * Wc[k * 2 + 0];
    o1 += p * Wc[k * 2 + 1];
  }
  out[g * 2 + 0] = o0;
  out[g * 2 + 1] = o1;
}

extern "C" void kernel_launch(void* const* d_in, const int* in_sizes, int n_in,
                              void* d_out, int out_size, void* d_ws, size_t ws_size,
                              hipStream_t stream) {
  const float* x  = (const float*)d_in[0];
  const int* src  = (const int*)d_in[1];
  const int* dst  = (const int*)d_in[2];
  const int* gid  = (const int*)d_in[3];
  const float* W1 = (const float*)d_in[5];
  const float* b1 = (const float*)d_in[6];
  const float* W2 = (const float*)d_in[7];
  const float* b2 = (const float*)d_in[8];
  const float* Wc = (const float*)d_in[9];
  const float* bc = (const float*)d_in[10];
  float* out = (float*)d_out;

  float* ws = (float*)d_ws;
  const size_t NF = (size_t)N_NODES * HID;           // 3.2M
  const size_t RN = (size_t)N_REL * N_NODES;         // 800k
  const size_t POOLF = N_GRAPHS * HID + N_GRAPHS;
  size_t wsf = ws_size / 4;

  const size_t T1_NEED = 22500000;   // ~90 MB

  if (wsf >= T1_NEED) {
    // ---- Tier 1 (round-7 layout) ----
    float* gpool = ws;                               // 128  (zero region start)
    float* gcnt  = gpool + N_GRAPHS * 2;             // 64
    float* rs_o  = gcnt + N_GRAPHS;                  // RN
    float* rs_i  = rs_o + RN;                        // RN
    int*   cnt   = (int*)(rs_i + RN);                // N_KEYS
    int*   fillc = cnt + N_KEYS;                     // N_KEYS (zero region end)
    int*   rp    = fillc + N_KEYS;                   // N_KEYS + 8
    int*   part  = rp + N_KEYS + 8;                  // 1024
    int*   ecol1 = part + 1024;                      // TOT_E
    int*   ecol2 = ecol1 + TOT_E;                    // TOT_E
    float* ew    = (float*)(ecol2 + TOT_E);          // TOT_E
    float* Ys2   = ew + TOT_E;                       // N*16
    ushort* Ys   = (ushort*)(Ys2 + (size_t)N_NODES * 16);   // N*256 ushorts
    ushort* Hbf  = Ys + (size_t)N_NODES * NCAT;             // N*32 ushorts
    ushort* Wt1  = Hbf + (size_t)N_NODES * HID;             // 256*128 ushorts
    ushort* Vt   = Wt1 + NCAT * IN_F;                       // 16*32 ushorts

    size_t zbytes = (N_GRAPHS * 3 + 2 * RN + 2 * (size_t)N_KEYS) * 4;   // ~12.8 MB
    hipMemsetAsync(ws, 0, zbytes, stream);

    deg_hist_kernel<<<1024, 256, 0, stream>>>(src, dst, (int*)rs_o, (int*)rs_i, cnt);
    rsqrt_kernel<<<(int)((2 * RN + 255) / 256), 256, 0, stream>>>(rs_o, (int)(2 * RN));
    prep_w_kernel<<<(NCAT * IN_F + 16 * HID + 255) / 256, 256, 0, stream>>>(W1, W2, Wc, Wt1, Vt);

    int sblocks = (N_KEYS + 1023) / 1024;
    scan1_kernel<<<sblocks, 256, 0, stream>>>(cnt, rp, part, N_KEYS);
    scan2_kernel<<<1, 256, 0, stream>>>(part, sblocks);
    scan3_kernel<<<(N_KEYS + 255) / 256, 256, 0, stream>>>(rp, part, N_KEYS);
    fill_kernel<<<1024, 256, 0, stream>>>(src, dst, rp, fillc, rs_i, ecol1, ecol2, ew);

    int gblocks = (N_NODES / 16 + 3) / 4;
    int nblocks = (N_NODES + 3) / 4;
    gemm_mfma<IN_F><<<gblocks, 256, 0, stream>>>(x, Wt1, rs_o, Ys, N_NODES);
    gather1_kernel<<<nblocks, 256, 0, stream>>>(Ys, ecol1, ew, rp, b1, Hbf);
    gemm2_mfma<<<gblocks, 256, 0, stream>>>(Hbf, Vt, rs_o, Ys2, N_NODES);
    gather2_pool_kernel<<<416, 256, 0, stream>>>(Ys2, ecol2, ew, rp, gid, gpool, gcnt);
    final_kernel<<<1, 64, 0, stream>>>(gpool, gcnt, b2, Wc, bc, out);
  } else {
    // ---- Tier 3: fp32 per-relation fallback, node-chunked hw ----
    float* acc1  = ws;
    float* acc2  = acc1 + NF;
    float* gpool = acc2 + NF;
    float* gcnt  = gpool + N_GRAPHS * HID;
    float* rsb   = ws + (2 * NF + POOLF);
    size_t zf = 2 * NF + POOLF;
    float* rs_o = rsb;
    float* rs_i = rsb + N_NODES;
    float* hw = rsb + 2 * N_NODES;
    size_t fixed3 = zf + 2 * N_NODES;
    size_t avail = (wsf > fixed3) ? (wsf - fixed3) : 0;
    long chunk = (long)(avail / HID) & ~255L;
    if (chunk < 256) chunk = 256;
    if (chunk > N_NODES) chunk = N_NODES;

    size_t zb = zf * 4; if (zb > ws_size) zb = ws_size;
    hipMemsetAsync(d_ws, 0, zb, stream);

    for (int layer = 0; layer < 2; layer++) {
      for (int r = 0; r < N_REL; r++) {
        hipMemsetAsync(rs_o, 0, 2 * N_NODES * 4, stream);
        deg_kernel<<<(N_EDGES + 255) / 256, 256, 0, stream>>>(src + (size_t)r * N_EDGES, dst + (size_t)r * N_EDGES,
                                                              (int*)rs_o, (int*)rs_i, 1);
        rsqrt_kernel<<<(2 * N_NODES + 255) / 256, 256, 0, stream>>>(rs_o, 2 * N_NODES);
        for (long n0 = 0; n0 < N_NODES; n0 += chunk) {
          long n1 = n0 + chunk; if (n1 > N_NODES) n1 = N_NODES;
          int tiles = (int)((n1 - n0 + TILE - 1) / TILE);
          if (layer == 0)
            proj1_kernel<<<dim3(tiles, 1), 256, 0, stream>>>(x, W1 + (size_t)r * IN_F * HID, rs_o, hw,
                                                             (int)n0, (int)n1, (int)chunk);
          else
            proj2_kernel<<<dim3(tiles, 1), 256, 0, stream>>>(acc1, b1, W2 + (size_t)r * HID * HID, rs_o, hw,
                                                             (int)n0, (int)n1, (int)chunk);
          long tot = (long)N_EDGES * HID;
          scatter_kernel<<<(int)((tot + 255) / 256), 256, 0, stream>>>(hw, src + (size_t)r * N_EDGES,
                                                                       dst + (size_t)r * N_EDGES, rs_i,
                                                                       layer == 0 ? acc1 : acc2,
                                                                       1, (int)n0, (int)n1, (int)chunk);
        }
      }
    }
    pool_kernel<<<256, 256, 0, stream>>>(acc2, b2, gid, gpool, gcnt);
    final3_kernel<<<1, 64, 0, stream>>>(gpool, gcnt, Wc, bc, out);
  }
}

// Round 11
// 340.160 us; speedup vs baseline: 1.5043x; 1.0699x over previous
//
#include <hip/hip_runtime.h>

// RGCN vulnerability classifier, fp32 in/out, MI355X.
// == Round-9 passing pipeline == (16-row bf16 MFMA gemm1 with rs_o epilogue; CSR-by-dst
// gather, merged relation buckets; layer2 collapsed via Vcat=W2@Wc; gather2 fused with
// pooling; deg_hist/fill XCD-partitioned grid-stride)
// + ONE change vs r9: degi eliminated — cnt[d*8+r] IS the in-degree histogram;
//   deg_hist does 2 atomics/edge and fill derives ew = rsqrtf(max(cnt,1)) inline
//   (same rsqrtf on the same int the old rs_i path used -> bitwise-identical weights).
// Tier-3 fp32 fallback for small ws.

#define N_NODES 100000
#define N_REL   8
#define N_EDGES 80000
#define IN_F    128
#define HID     32
#define N_GRAPHS 64
#define NCAT    (N_REL * HID)       // 256
#define N_KEYS  (N_NODES * N_REL)   // 800000
#define TOT_E   (N_REL * N_EDGES)   // 640000
#define DRANGE  12500               // N_NODES / 8 teams

constexpr int TILE = 256;   // tier-3 projection block
constexpr int KC   = 32;

typedef __attribute__((ext_vector_type(8))) short bf16x8;
typedef __attribute__((ext_vector_type(4))) float f32x4;

__device__ __forceinline__ ushort f2bf(float v) {
  unsigned u = __builtin_bit_cast(unsigned, v);
  u = (u + 0x7fffu + ((u >> 16) & 1u)) >> 16;   // RNE
  return (ushort)u;
}
__device__ __forceinline__ float bf2f(ushort h) {
  unsigned u = ((unsigned)h) << 16;
  return __builtin_bit_cast(float, u);
}

// out-degree + CSR histogram (cnt doubles as in-degree), XCD-partitioned teams.
__global__ __launch_bounds__(256) void deg_hist_kernel(const int* __restrict__ src, const int* __restrict__ dst,
                                                       int* __restrict__ dego, int* __restrict__ cnt) {
  int q = blockIdx.x & 7;
  int bb = blockIdx.x >> 3;
  int nb = gridDim.x >> 3;
  for (int i = bb * 256 + threadIdx.x; i < TOT_E; i += nb * 256) {
    int s = src[i], d = dst[i];
    int r = i / N_EDGES;
    if (s / DRANGE == q) atomicAdd(&dego[r * N_NODES + s], 1);
    if (d / DRANGE == q) atomicAdd(&cnt[d * N_REL + r], 1);
  }
}

__global__ __launch_bounds__(256) void rsqrt_kernel(float* __restrict__ p, int count) {
  int i = blockIdx.x * 256 + threadIdx.x;
  if (i < count) {
    int d = ((const int*)p)[i];
    p[i] = rsqrtf((float)(d < 1 ? 1 : d));
  }
}

// Wt1[n][k] = bf16(W1[r][k][j]), n=r*32+j (B^T for MFMA).
// Vt[n][k] = bf16( sum_j W2[r][k][j]*Wc[j][c] ), n=r*2+c (W2@Wc fold).
__global__ __launch_bounds__(256) void prep_w_kernel(const float* __restrict__ W1, const float* __restrict__ W2,
                                                     const float* __restrict__ Wc,
                                                     ushort* __restrict__ Wt1, ushort* __restrict__ Vt) {
  int i = blockIdx.x * 256 + threadIdx.x;
  if (i < NCAT * IN_F) {
    int n = i >> 7, k = i & 127;
    int r = n >> 5, j = n & 31;
    Wt1[i] = f2bf(W1[r * (IN_F * HID) + k * HID + j]);
  } else {
    int q = i - NCAT * IN_F;
    if (q < 16 * HID) {
      int n = q >> 5, k = q & 31;
      int r = n >> 1, c = n & 1;
      float s = 0.f;
#pragma unroll
      for (int j = 0; j < HID; j++) s += W2[r * (HID * HID) + k * HID + j] * Wc[j * 2 + c];
      Vt[q] = f2bf(s);
    }
  }
}

// ---- exclusive scan over cnt[N_KEYS] -> rp ----
__global__ __launch_bounds__(256) void scan1_kernel(const int* __restrict__ in, int* __restrict__ out,
                                                    int* __restrict__ partial, int n) {
  __shared__ int ts[256];
  int b0 = blockIdx.x * 1024;
  int t = threadIdx.x;
  int v[4]; int s = 0;
#pragma unroll
  for (int k = 0; k < 4; k++) {
    int idx = b0 + t * 4 + k;
    v[k] = s;
    s += (idx < n) ? in[idx] : 0;
  }
  ts[t] = s;
  __syncthreads();
  for (int off = 1; off < 256; off <<= 1) {
    int xv = (t >= off) ? ts[t - off] : 0;
    __syncthreads();
    ts[t] += xv;
    __syncthreads();
  }
  int texcl = (t == 0) ? 0 : ts[t - 1];
#pragma unroll
  for (int k = 0; k < 4; k++) {
    int idx = b0 + t * 4 + k;
    if (idx < n) out[idx] = texcl + v[k];
  }
  if (t == 255) partial[blockIdx.x] = ts[255];
}

__global__ __launch_bounds__(256) void scan2_kernel(int* __restrict__ partial, int nb) {
  __shared__ int ts[256];
  int t = threadIdx.x;
  int v[4]; int s = 0;
#pragma unroll
  for (int k = 0; k < 4; k++) {
    int idx = t * 4 + k;
    v[k] = s;
    s += (idx < nb) ? partial[idx] : 0;
  }
  ts[t] = s;
  __syncthreads();
  for (int off = 1; off < 256; off <<= 1) {
    int xv = (t >= off) ? ts[t - off] : 0;
    __syncthreads();
    ts[t] += xv;
    __syncthreads();
  }
  int texcl = (t == 0) ? 0 : ts[t - 1];
#pragma unroll
  for (int k = 0; k < 4; k++) {
    int idx = t * 4 + k;
    if (idx < nb) partial[idx] = texcl + v[k];
  }
}

__global__ __launch_bounds__(256) void scan3_kernel(int* __restrict__ out, const int* __restrict__ partial, int n) {
  int i = blockIdx.x * 256 + threadIdx.x;
  if (i < n) out[i] += partial[i >> 10];
  if (i == 0) out[n] = TOT_E;
}

// CSR fill, XCD-partitioned by d-ownership. ew computed inline from cnt (bitwise
// identical to r9's rsqrt_kernel->rs_i path: same rsqrtf on the same int).
__global__ __launch_bounds__(256) void fill_kernel(const int* __restrict__ src, const int* __restrict__ dst,
                                                   const int* __restrict__ rp, int* __restrict__ fillc,
                                                   const int* __restrict__ cnt,
                                                   int* __restrict__ ecol1, int* __restrict__ ecol2,
                                                   float* __restrict__ ew) {
  int q = blockIdx.x & 7;
  int bb = blockIdx.x >> 3;
  int nb = gridDim.x >> 3;
  for (int i = bb * 256 + threadIdx.x; i < TOT_E; i += nb * 256) {
    int d = dst[i];
    if (d / DRANGE != q) continue;
    int s = src[i];
    int r = i / N_EDGES;
    int key = d * N_REL + r;
    int c = cnt[key];
    int pos = atomicAdd(&fillc[key], 1);
    int t = rp[key] + pos;
    ecol1[t] = s * NCAT + r * HID;       // ushort index into Ys
    ecol2[t] = s * 16 + r * 2;           // float index into Ys2
    ew[t] = rsqrtf((float)(c < 1 ? 1 : c));
  }
}

// MFMA GEMM layer1 (r9's exact 16-row version):
// Ys[M x 256] = bf16( (fp32 x @ Wcat) * rs_o[r][m] ), cast fused in A-load.
template<int K>
__global__ __launch_bounds__(256) void gemm_mfma(const float* __restrict__ A, const ushort* __restrict__ Bt,
                                                 const float* __restrict__ rs_o, ushort* __restrict__ Y, int M) {
  __shared__ ushort yt[4][16 * 260];
  int wave = __builtin_amdgcn_readfirstlane(threadIdx.x >> 6);
  int lane = threadIdx.x & 63;
  int m0 = (blockIdx.x * 4 + wave) * 16;
  if (m0 >= M) return;
  int row = lane & 15, quad = lane >> 4;
  f32x4 acc[16];
#pragma unroll
  for (int nt = 0; nt < 16; nt++) acc[nt] = (f32x4){0.f, 0.f, 0.f, 0.f};
#pragma unroll
  for (int kq = 0; kq < K / 32; kq++) {
    const float* ap = &A[(size_t)(m0 + row) * K + kq * 32 + quad * 8];
    float4 a0 = *(const float4*)ap;
    float4 a1 = *(const float4*)(ap + 4);
    bf16x8 a;
    a[0] = (short)f2bf(a0.x); a[1] = (short)f2bf(a0.y); a[2] = (short)f2bf(a0.z); a[3] = (short)f2bf(a0.w);
    a[4] = (short)f2bf(a1.x); a[5] = (short)f2bf(a1.y); a[6] = (short)f2bf(a1.z); a[7] = (short)f2bf(a1.w);
#pragma unroll
    for (int nt = 0; nt < 16; nt++) {
      bf16x8 b = *(const bf16x8*)&Bt[(size_t)(nt * 16 + row) * K + kq * 32 + quad * 8];
      acc[nt] = __builtin_amdgcn_mfma_f32_16x16x32_bf16(a, b, acc[nt], 0, 0, 0);
    }
  }
  float4 sc[N_REL];
#pragma unroll
  for (int r = 0; r < N_REL; r++)
    sc[r] = *(const float4*)&rs_o[(size_t)r * N_NODES + m0 + quad * 4];
  ushort* myt = &yt[wave][0];
#pragma unroll
  for (int nt = 0; nt < 16; nt++) {
    const float* s4 = (const float*)&sc[nt >> 1];
#pragma unroll
    for (int i = 0; i < 4; i++)
      myt[(quad * 4 + i) * 260 + nt * 16 + row] = f2bf(acc[nt][i] * s4[i]);
  }
  ushort* ybase = &Y[(size_t)m0 * NCAT];
#pragma unroll
  for (int k = 0; k < 8; k++) {
    int g = k * 512 + lane * 8;
    int r2 = g >> 8, c2 = g & 255;
    const ushort* sp = &myt[r2 * 260 + c2];
    uint4 v;
    v.x = *(const uint*)(sp + 0);
    v.y = *(const uint*)(sp + 2);
    v.z = *(const uint*)(sp + 4);
    v.w = *(const uint*)(sp + 6);
    *(uint4*)&ybase[g] = v;
  }
}

// MFMA GEMM layer2 (collapsed): Ys2[M x 16] fp32 = (H[M x 32] @ Vcat[32 x 16]) * rs_o[r][m], r = col>>1.
__global__ __launch_bounds__(256) void gemm2_mfma(const ushort* __restrict__ H, const ushort* __restrict__ Vt,
                                                  const float* __restrict__ rs_o, float* __restrict__ Ys2, int M) {
  int wave = __builtin_amdgcn_readfirstlane(threadIdx.x >> 6);
  int lane = threadIdx.x & 63;
  int m0 = (blockIdx.x * 4 + wave) * 16;
  if (m0 >= M) return;
  int row = lane & 15, quad = lane >> 4;
  f32x4 acc = (f32x4){0.f, 0.f, 0.f, 0.f};
  bf16x8 a = *(const bf16x8*)&H[(size_t)(m0 + row) * HID + quad * 8];
  bf16x8 b = *(const bf16x8*)&Vt[row * HID + quad * 8];
  acc = __builtin_amdgcn_mfma_f32_16x16x32_bf16(a, b, acc, 0, 0, 0);
  int r = row >> 1;
#pragma unroll
  for (int i = 0; i < 4; i++) {
    int m = m0 + quad * 4 + i;
    Ys2[(size_t)m * 16 + row] = acc[i] * rs_o[(size_t)r * N_NODES + m];
  }
}

// Gather layer1, merged relation buckets: one wave per dst node; lane&31 = feature,
// lane>>5 = 2-way slot parallelism over the node's contiguous slot range.
__global__ __launch_bounds__(256) void gather1_kernel(const ushort* __restrict__ Ys, const int* __restrict__ ecol1,
                                                      const float* __restrict__ ew, const int* __restrict__ rp,
                                                      const float* __restrict__ b1, ushort* __restrict__ H) {
  int wave = __builtin_amdgcn_readfirstlane(threadIdx.x >> 6);
  int lane = threadIdx.x & 63;
  int d = blockIdx.x * 4 + wave;
  if (d >= N_NODES) return;
  int j = lane & 31, half = lane >> 5;
  int base = rp[d * N_REL], endp = rp[d * N_REL + N_REL];
  float sum = 0.f;
  for (int t = base + half; t < endp; t += 2) {
    int off = ecol1[t];
    float w = ew[t];
    sum += w * bf2f(Ys[(size_t)off + j]);
  }
  sum += __shfl_down(sum, 32);
  if (half == 0) {
    float sb = 0.f;
#pragma unroll
    for (int q = 0; q < N_REL; q++) sb += b1[q * HID + j];
    H[(size_t)d * HID + j] = f2bf(fmaxf(sum + sb, 0.f));
  }
}

// Gather layer2 fused with per-graph pooling.
__global__ __launch_bounds__(256) void gather2_pool_kernel(const float* __restrict__ Ys2,
                                                           const int* __restrict__ ecol2,
                                                           const float* __restrict__ ew, const int* __restrict__ rp,
                                                           const int* __restrict__ gid,
                                                           float* __restrict__ gpool, float* __restrict__ gcnt) {
  __shared__ float lp[N_GRAPHS * 2];
  __shared__ float lc[N_GRAPHS];
  int t = threadIdx.x;
  if (t < N_GRAPHS * 2) lp[t] = 0.f;
  if (t < N_GRAPHS) lc[t] = 0.f;
  __syncthreads();
  for (int n = blockIdx.x * 256 + t; n < N_NODES; n += gridDim.x * 256) {
    int base = rp[n * N_REL], endp = rp[n * N_REL + N_REL];
    float z0 = 0.f, z1 = 0.f;
    for (int s = base; s < endp; s++) {
      float w = ew[s];
      float2 y = *(const float2*)&Ys2[ecol2[s]];
      z0 += w * y.x;
      z1 += w * y.y;
    }
    int g = gid[n];
    atomicAdd(&lp[g * 2 + 0], z0);
    atomicAdd(&lp[g * 2 + 1], z1);
    atomicAdd(&lc[g], 1.f);
  }
  __syncthreads();
  if (t < N_GRAPHS * 2) atomicAdd(&gpool[t], lp[t]);
  if (t < N_GRAPHS) atomicAdd(&gcnt[t], lc[t]);
}

// out[g] = gpool[g]/cnt + (sum_r b2[r]) @ Wc + bc   (cnt==0 -> bc exactly)
__global__ void final_kernel(const float* __restrict__ gpool, const float* __restrict__ gcnt,
                             const float* __restrict__ b2, const float* __restrict__ Wc,
                             const float* __restrict__ bc, float* __restrict__ out) {
  int g = threadIdx.x;
  if (g >= N_GRAPHS) return;
  float c0 = 0.f, c1 = 0.f;
#pragma unroll
  for (int k = 0; k < HID; k++) {
    float sb = 0.f;
#pragma unroll
    for (int r = 0; r < N_REL; r++) sb += b2[r * HID + k];
    c0 += sb * Wc[k * 2 + 0];
    c1 += sb * Wc[k * 2 + 1];
  }
  float cntv = gcnt[g];
  if (cntv > 0.f) {
    out[g * 2 + 0] = gpool[g * 2 + 0] / cntv + c0 + bc[0];
    out[g * 2 + 1] = gpool[g * 2 + 1] / cntv + c1 + bc[1];
  } else {
    out[g * 2 + 0] = bc[0];
    out[g * 2 + 1] = bc[1];
  }
}

// ---- Tier-3 fp32 fallback kernels (small ws) ----
__global__ __launch_bounds__(256) void deg_kernel(const int* __restrict__ src, const int* __restrict__ dst,
                                                  int* __restrict__ dego, int* __restrict__ degi, int n_rel) {
  int i = blockIdx.x * 256 + threadIdx.x;
  if (i < n_rel * N_EDGES) {
    int r = i / N_EDGES;
    atomicAdd(&dego[r * N_NODES + src[i]], 1);
    atomicAdd(&degi[r * N_NODES + dst[i]], 1);
  }
}

__global__ __launch_bounds__(256) void proj1_kernel(const float* __restrict__ x, const float* __restrict__ W1r0,
                                                    const float* __restrict__ rs_o, float* __restrict__ hw,
                                                    int n0, int n1, int hw_nodes) {
  int rr = blockIdx.y;
  int nb = n0 + blockIdx.x * TILE;
  int t = threadIdx.x;
  __shared__ float xs[TILE][KC + 4];
  const float* __restrict__ Wr = W1r0 + (size_t)rr * (IN_F * HID);
  float acc[HID];
#pragma unroll
  for (int j = 0; j < HID; j++) acc[j] = 0.f;
  for (int kc = 0; kc < IN_F; kc += KC) {
    __syncthreads();
#pragma unroll
    for (int i = 0; i < (TILE * KC / 4) / 256; i++) {
      int q = t + i * 256;
      int nn = q >> 3, k4 = q & 7;
      int n = nb + nn;
      float4 v = make_float4(0.f, 0.f, 0.f, 0.f);
      if (n < n1) v = *(const float4*)&x[(size_t)n * IN_F + kc + k4 * 4];
      *(float4*)&xs[nn][k4 * 4] = v;
    }
    __syncthreads();
#pragma unroll
    for (int k4 = 0; k4 < KC / 4; k4++) {
      float4 xv = *(const float4*)&xs[t][k4 * 4];
      const float* wk = &Wr[(kc + k4 * 4) * HID];
#pragma unroll
      for (int j = 0; j < HID; j++) acc[j] += xv.x * wk[j];
#pragma unroll
      for (int j = 0; j < HID; j++) acc[j] += xv.y * wk[HID + j];
#pragma unroll
      for (int j = 0; j < HID; j++) acc[j] += xv.z * wk[2 * HID + j];
#pragma unroll
      for (int j = 0; j < HID; j++) acc[j] += xv.w * wk[3 * HID + j];
    }
  }
  int n = nb + t;
  if (n < n1) {
    float s = rs_o[(size_t)rr * N_NODES + n];
    float* o = &hw[((size_t)rr * hw_nodes + (n - n0)) * HID];
#pragma unroll
    for (int j4 = 0; j4 < HID / 4; j4++) {
      float4 v = make_float4(acc[j4 * 4] * s, acc[j4 * 4 + 1] * s, acc[j4 * 4 + 2] * s, acc[j4 * 4 + 3] * s);
      *(float4*)&o[j4 * 4] = v;
    }
  }
}

__global__ __launch_bounds__(256) void proj2_kernel(const float* __restrict__ acc1, const float* __restrict__ b1,
                                                    const float* __restrict__ W2r0, const float* __restrict__ rs_o,
                                                    float* __restrict__ hw, int n0, int n1, int hw_nodes) {
  int n = n0 + blockIdx.x * 256 + threadIdx.x;
  if (n >= n1) return;
  int rr = blockIdx.y;
  float h1[HID];
#pragma unroll
  for (int j4 = 0; j4 < HID / 4; j4++) {
    float4 v = *(const float4*)&acc1[(size_t)n * HID + j4 * 4];
    h1[j4 * 4 + 0] = v.x; h1[j4 * 4 + 1] = v.y; h1[j4 * 4 + 2] = v.z; h1[j4 * 4 + 3] = v.w;
  }
#pragma unroll
  for (int j = 0; j < HID; j++) {
    float sb = 0.f;
#pragma unroll
    for (int q = 0; q < N_REL; q++) sb += b1[q * HID + j];
    h1[j] = fmaxf(h1[j] + sb, 0.f);
  }
  const float* __restrict__ Wr = W2r0 + (size_t)rr * (HID * HID);
  float acc[HID];
#pragma unroll
  for (int j = 0; j < HID; j++) acc[j] = 0.f;
#pragma unroll
  for (int k = 0; k < HID; k++) {
    float hv = h1[k];
#pragma unroll
    for (int j = 0; j < HID; j++) acc[j] += hv * Wr[k * HID + j];
  }
  float s = rs_o[(size_t)rr * N_NODES + n];
  float* o = &hw[((size_t)rr * hw_nodes + (n - n0)) * HID];
#pragma unroll
  for (int j4 = 0; j4 < HID / 4; j4++) {
    float4 v = make_float4(acc[j4 * 4] * s, acc[j4 * 4 + 1] * s, acc[j4 * 4 + 2] * s, acc[j4 * 4 + 3] * s);
    *(float4*)&o[j4 * 4] = v;
  }
}

__global__ __launch_bounds__(256) void scatter_kernel(const float* __restrict__ hw, const int* __restrict__ src,
                                                      const int* __restrict__ dst, const float* __restrict__ rs_i,
                                                      float* __restrict__ acc, int nr, int n0, int n1, int hw_nodes) {
  long i = (long)blockIdx.x * 256 + threadIdx.x;
  long total = (long)nr * N_EDGES * HID;
  if (i >= total) return;
  int j = (int)(i & (HID - 1));
  long e = i >> 5;
  int rr = (int)(e / N_EDGES);
  int ee = (int)(e - (long)rr * N_EDGES);
  int s = src[rr * N_EDGES + ee];
  if (s < n0 || s >= n1) return;
  int d = dst[rr * N_EDGES + ee];
  float v = hw[((size_t)rr * hw_nodes + (s - n0)) * HID + j] * rs_i[(size_t)rr * N_NODES + d];
  atomicAdd(&acc[(size_t)d * HID + j], v);
}

__global__ __launch_bounds__(256) void pool_kernel(const float* __restrict__ acc2, const float* __restrict__ b2,
                                                   const int* __restrict__ gid, float* __restrict__ gpool,
                                                   float* __restrict__ gcnt) {
  __shared__ float lp[N_GRAPHS * HID];
  __shared__ float lc[N_GRAPHS];
  int t = threadIdx.x;
  for (int i = t; i < N_GRAPHS * HID; i += 256) lp[i] = 0.f;
  if (t < N_GRAPHS) lc[t] = 0.f;
  __syncthreads();
  int j = t & (HID - 1);
  int grp = t >> 5;
  float sb = 0.f;
#pragma unroll
  for (int q = 0; q < N_REL; q++) sb += b2[q * HID + j];
  for (int n = blockIdx.x * 8 + grp; n < N_NODES; n += gridDim.x * 8) {
    int g = gid[n];
    float v = acc2[(size_t)n * HID + j] + sb;
    atomicAdd(&lp[g * HID + j], v);
    if (j == 0) atomicAdd(&lc[g], 1.f);
  }
  __syncthreads();
  for (int i = t; i < N_GRAPHS * HID; i += 256) atomicAdd(&gpool[i], lp[i]);
  if (t < N_GRAPHS) atomicAdd(&gcnt[t], lc[t]);
}

__global__ void final3_kernel(const float* __restrict__ gpool, const float* __restrict__ gcnt,
                              const float* __restrict__ Wc, const float* __restrict__ bc,
                              float* __restrict__ out) {
  int g = threadIdx.x;
  if (g >= N_GRAPHS) return;
  float inv = 1.f / fmaxf(gcnt[g], 1.f);
  float o0 = bc[0], o1 = bc[1];
#pragma unroll
  for (int k = 0; k < HID; k++) {
    float p = gpool[g * HID + k] * inv;
    o0 += p * Wc[k * 2 + 0];
    o1 += p * Wc[k * 2 + 1];
  }
  out[g * 2 + 0] = o0;
  out[g * 2 + 1] = o1;
}

extern "C" void kernel_launch(void* const* d_in, const int* in_sizes, int n_in,
                              void* d_out, int out_size, void* d_ws, size_t ws_size,
                              hipStream_t stream) {
  const float* x  = (const float*)d_in[0];
  const int* src  = (const int*)d_in[1];
  const int* dst  = (const int*)d_in[2];
  const int* gid  = (const int*)d_in[3];
  const float* W1 = (const float*)d_in[5];
  const float* b1 = (const float*)d_in[6];
  const float* W2 = (const float*)d_in[7];
  const float* b2 = (const float*)d_in[8];
  const float* Wc = (const float*)d_in[9];
  const float* bc = (const float*)d_in[10];
  float* out = (float*)d_out;

  float* ws = (float*)d_ws;
  const size_t NF = (size_t)N_NODES * HID;           // 3.2M
  const size_t RN = (size_t)N_REL * N_NODES;         // 800k
  const size_t POOLF = N_GRAPHS * HID + N_GRAPHS;
  size_t wsf = ws_size / 4;

  const size_t T1_NEED = 22500000;   // ~90 MB (actual ~21.0M float slots)

  if (wsf >= T1_NEED) {
    // ---- Tier 1 layout ----
    float* gpool = ws;                               // 128  (zero region start)
    float* gcnt  = gpool + N_GRAPHS * 2;             // 64
    float* rs_o  = gcnt + N_GRAPHS;                  // RN (int deg -> rsqrt in place)
    int*   cnt   = (int*)(rs_o + RN);                // N_KEYS (raw in-degree counts)
    int*   fillc = cnt + N_KEYS;                     // N_KEYS (zero region end)
    int*   rp    = fillc + N_KEYS;                   // N_KEYS + 8
    int*   part  = rp + N_KEYS + 8;                  // 1024
    int*   ecol1 = part + 1024;                      // TOT_E
    int*   ecol2 = ecol1 + TOT_E;                    // TOT_E
    float* ew    = (float*)(ecol2 + TOT_E);          // TOT_E
    float* Ys2   = ew + TOT_E;                       // N*16
    ushort* Ys   = (ushort*)(Ys2 + (size_t)N_NODES * 16);   // N*256 ushorts
    ushort* Hbf  = Ys + (size_t)N_NODES * NCAT;             // N*32 ushorts
    ushort* Wt1  = Hbf + (size_t)N_NODES * HID;             // 256*128 ushorts
    ushort* Vt   = Wt1 + NCAT * IN_F;                       // 16*32 ushorts

    size_t zbytes = (N_GRAPHS * 3 + RN + 2 * (size_t)N_KEYS) * 4;   // ~9.6 MB
    hipMemsetAsync(ws, 0, zbytes, stream);

    deg_hist_kernel<<<1024, 256, 0, stream>>>(src, dst, (int*)rs_o, cnt);
    rsqrt_kernel<<<(int)((RN + 255) / 256), 256, 0, stream>>>(rs_o, (int)RN);
    prep_w_kernel<<<(NCAT * IN_F + 16 * HID + 255) / 256, 256, 0, stream>>>(W1, W2, Wc, Wt1, Vt);

    int sblocks = (N_KEYS + 1023) / 1024;
    scan1_kernel<<<sblocks, 256, 0, stream>>>(cnt, rp, part, N_KEYS);
    scan2_kernel<<<1, 256, 0, stream>>>(part, sblocks);
    scan3_kernel<<<(N_KEYS + 255) / 256, 256, 0, stream>>>(rp, part, N_KEYS);
    fill_kernel<<<1024, 256, 0, stream>>>(src, dst, rp, fillc, cnt, ecol1, ecol2, ew);

    int gblocks = (N_NODES / 16 + 3) / 4;
    int nblocks = (N_NODES + 3) / 4;
    gemm_mfma<IN_F><<<gblocks, 256, 0, stream>>>(x, Wt1, rs_o, Ys, N_NODES);
    gather1_kernel<<<nblocks, 256, 0, stream>>>(Ys, ecol1, ew, rp, b1, Hbf);
    gemm2_mfma<<<gblocks, 256, 0, stream>>>(Hbf, Vt, rs_o, Ys2, N_NODES);
    gather2_pool_kernel<<<416, 256, 0, stream>>>(Ys2, ecol2, ew, rp, gid, gpool, gcnt);
    final_kernel<<<1, 64, 0, stream>>>(gpool, gcnt, b2, Wc, bc, out);
  } else {
    // ---- Tier 3: fp32 per-relation fallback, node-chunked hw ----
    float* acc1  = ws;
    float* acc2  = acc1 + NF;
    float* gpool = acc2 + NF;
    float* gcnt  = gpool + N_GRAPHS * HID;
    float* rsb   = ws + (2 * NF + POOLF);
    size_t zf = 2 * NF + POOLF;
    float* rs_o = rsb;
    float* rs_i = rsb + N_NODES;
    float* hw = rsb + 2 * N_NODES;
    size_t fixed3 = zf + 2 * N_NODES;
    size_t avail = (wsf > fixed3) ? (wsf - fixed3) : 0;
    long chunk = (long)(avail / HID) & ~255L;
    if (chunk < 256) chunk = 256;
    if (chunk > N_NODES) chunk = N_NODES;

    size_t zb = zf * 4; if (zb > ws_size) zb = ws_size;
    hipMemsetAsync(d_ws, 0, zb, stream);

    for (int layer = 0; layer < 2; layer++) {
      for (int r = 0; r < N_REL; r++) {
        hipMemsetAsync(rs_o, 0, 2 * N_NODES * 4, stream);
        deg_kernel<<<(N_EDGES + 255) / 256, 256, 0, stream>>>(src + (size_t)r * N_EDGES, dst + (size_t)r * N_EDGES,
                                                              (int*)rs_o, (int*)rs_i, 1);
        rsqrt_kernel<<<(2 * N_NODES + 255) / 256, 256, 0, stream>>>(rs_o, 2 * N_NODES);
        for (long n0 = 0; n0 < N_NODES; n0 += chunk) {
          long n1 = n0 + chunk; if (n1 > N_NODES) n1 = N_NODES;
          int tiles = (int)((n1 - n0 + TILE - 1) / TILE);
          if (layer == 0)
            proj1_kernel<<<dim3(tiles, 1), 256, 0, stream>>>(x, W1 + (size_t)r * IN_F * HID, rs_o, hw,
                                                             (int)n0, (int)n1, (int)chunk);
          else
            proj2_kernel<<<dim3(tiles, 1), 256, 0, stream>>>(acc1, b1, W2 + (size_t)r * HID * HID, rs_o, hw,
                                                             (int)n0, (int)n1, (int)chunk);
          long tot = (long)N_EDGES * HID;
          scatter_kernel<<<(int)((tot + 255) / 256), 256, 0, stream>>>(hw, src + (size_t)r * N_EDGES,
                                                                       dst + (size_t)r * N_EDGES, rs_i,
                                                                       layer == 0 ? acc1 : acc2,
                                                                       1, (int)n0, (int)n1, (int)chunk);
        }
      }
    }
    pool_kernel<<<256, 256, 0, stream>>>(acc2, b2, gid, gpool, gcnt);
    final3_kernel<<<1, 64, 0, stream>>>(gpool, gcnt, Wc, bc, out);
  }
}

// Round 12
// 290.522 us; speedup vs baseline: 1.7614x; 1.1709x over previous
//
#include <hip/hip_runtime.h>

// RGCN vulnerability classifier, fp32 in/out, MI355X.
// r11 pipeline (passing, 340us) + ONE change: gemm1 stages Bt in LDS (two 128-row
// phases, stride-136 conflict-free layout, A-frags hoisted to regs), r11's proven
// single-phase transpose epilogue reused after a barrier. Everything else identical.
// Tier-3 fp32 fallback for small ws.

#define N_NODES 100000
#define N_REL   8
#define N_EDGES 80000
#define IN_F    128
#define HID     32
#define N_GRAPHS 64
#define NCAT    (N_REL * HID)       // 256
#define N_KEYS  (N_NODES * N_REL)   // 800000
#define TOT_E   (N_REL * N_EDGES)   // 640000
#define DRANGE  12500               // N_NODES / 8 teams

constexpr int TILE = 256;   // tier-3 projection block
constexpr int KC   = 32;

typedef __attribute__((ext_vector_type(8))) short bf16x8;
typedef __attribute__((ext_vector_type(4))) float f32x4;

__device__ __forceinline__ ushort f2bf(float v) {
  unsigned u = __builtin_bit_cast(unsigned, v);
  u = (u + 0x7fffu + ((u >> 16) & 1u)) >> 16;   // RNE
  return (ushort)u;
}
__device__ __forceinline__ float bf2f(ushort h) {
  unsigned u = ((unsigned)h) << 16;
  return __builtin_bit_cast(float, u);
}

// out-degree + CSR histogram (cnt doubles as in-degree), XCD-partitioned teams.
__global__ __launch_bounds__(256) void deg_hist_kernel(const int* __restrict__ src, const int* __restrict__ dst,
                                                       int* __restrict__ dego, int* __restrict__ cnt) {
  int q = blockIdx.x & 7;
  int bb = blockIdx.x >> 3;
  int nb = gridDim.x >> 3;
  for (int i = bb * 256 + threadIdx.x; i < TOT_E; i += nb * 256) {
    int s = src[i], d = dst[i];
    int r = i / N_EDGES;
    if (s / DRANGE == q) atomicAdd(&dego[r * N_NODES + s], 1);
    if (d / DRANGE == q) atomicAdd(&cnt[d * N_REL + r], 1);
  }
}

__global__ __launch_bounds__(256) void rsqrt_kernel(float* __restrict__ p, int count) {
  int i = blockIdx.x * 256 + threadIdx.x;
  if (i < count) {
    int d = ((const int*)p)[i];
    p[i] = rsqrtf((float)(d < 1 ? 1 : d));
  }
}

// Wt1[n][k] = bf16(W1[r][k][j]), n=r*32+j (B^T for MFMA).
// Vt[n][k] = bf16( sum_j W2[r][k][j]*Wc[j][c] ), n=r*2+c (W2@Wc fold).
__global__ __launch_bounds__(256) void prep_w_kernel(const float* __restrict__ W1, const float* __restrict__ W2,
                                                     const float* __restrict__ Wc,
                                                     ushort* __restrict__ Wt1, ushort* __restrict__ Vt) {
  int i = blockIdx.x * 256 + threadIdx.x;
  if (i < NCAT * IN_F) {
    int n = i >> 7, k = i & 127;
    int r = n >> 5, j = n & 31;
    Wt1[i] = f2bf(W1[r * (IN_F * HID) + k * HID + j]);
  } else {
    int q = i - NCAT * IN_F;
    if (q < 16 * HID) {
      int n = q >> 5, k = q & 31;
      int r = n >> 1, c = n & 1;
      float s = 0.f;
#pragma unroll
      for (int j = 0; j < HID; j++) s += W2[r * (HID * HID) + k * HID + j] * Wc[j * 2 + c];
      Vt[q] = f2bf(s);
    }
  }
}

// ---- exclusive scan over cnt[N_KEYS] -> rp ----
__global__ __launch_bounds__(256) void scan1_kernel(const int* __restrict__ in, int* __restrict__ out,
                                                    int* __restrict__ partial, int n) {
  __shared__ int ts[256];
  int b0 = blockIdx.x * 1024;
  int t = threadIdx.x;
  int v[4]; int s = 0;
#pragma unroll
  for (int k = 0; k < 4; k++) {
    int idx = b0 + t * 4 + k;
    v[k] = s;
    s += (idx < n) ? in[idx] : 0;
  }
  ts[t] = s;
  __syncthreads();
  for (int off = 1; off < 256; off <<= 1) {
    int xv = (t >= off) ? ts[t - off] : 0;
    __syncthreads();
    ts[t] += xv;
    __syncthreads();
  }
  int texcl = (t == 0) ? 0 : ts[t - 1];
#pragma unroll
  for (int k = 0; k < 4; k++) {
    int idx = b0 + t * 4 + k;
    if (idx < n) out[idx] = texcl + v[k];
  }
  if (t == 255) partial[blockIdx.x] = ts[255];
}

__global__ __launch_bounds__(256) void scan2_kernel(int* __restrict__ partial, int nb) {
  __shared__ int ts[256];
  int t = threadIdx.x;
  int v[4]; int s = 0;
#pragma unroll
  for (int k = 0; k < 4; k++) {
    int idx = t * 4 + k;
    v[k] = s;
    s += (idx < nb) ? partial[idx] : 0;
  }
  ts[t] = s;
  __syncthreads();
  for (int off = 1; off < 256; off <<= 1) {
    int xv = (t >= off) ? ts[t - off] : 0;
    __syncthreads();
    ts[t] += xv;
    __syncthreads();
  }
  int texcl = (t == 0) ? 0 : ts[t - 1];
#pragma unroll
  for (int k = 0; k < 4; k++) {
    int idx = t * 4 + k;
    if (idx < nb) partial[idx] = texcl + v[k];
  }
}

__global__ __launch_bounds__(256) void scan3_kernel(int* __restrict__ out, const int* __restrict__ partial, int n) {
  int i = blockIdx.x * 256 + threadIdx.x;
  if (i < n) out[i] += partial[i >> 10];
  if (i == 0) out[n] = TOT_E;
}

// CSR fill, XCD-partitioned by d-ownership; ew derived inline from cnt.
__global__ __launch_bounds__(256) void fill_kernel(const int* __restrict__ src, const int* __restrict__ dst,
                                                   const int* __restrict__ rp, int* __restrict__ fillc,
                                                   const int* __restrict__ cnt,
                                                   int* __restrict__ ecol1, int* __restrict__ ecol2,
                                                   float* __restrict__ ew) {
  int q = blockIdx.x & 7;
  int bb = blockIdx.x >> 3;
  int nb = gridDim.x >> 3;
  for (int i = bb * 256 + threadIdx.x; i < TOT_E; i += nb * 256) {
    int d = dst[i];
    if (d / DRANGE != q) continue;
    int s = src[i];
    int r = i / N_EDGES;
    int key = d * N_REL + r;
    int c = cnt[key];
    int pos = atomicAdd(&fillc[key], 1);
    int t = rp[key] + pos;
    ecol1[t] = s * NCAT + r * HID;       // ushort index into Ys
    ecol2[t] = s * 16 + r * 2;           // float index into Ys2
    ew[t] = rsqrtf((float)(c < 1 ? 1 : c));
  }
}

// MFMA GEMM layer1 with LDS-staged B:
// Ys[M x 256] = bf16( (fp32 x @ Wcat) * rs_o[r][m] ). Two 128-row B phases staged at
// stride 136 ushorts (conflict-free b128 reads: bank = (68*row+4*quad)%32 covers all
// 32 banks at 8 dwords each). A-frags hoisted once. r11's proven single-phase
// transpose epilogue, reusing the staging LDS after __syncthreads. No early returns
// (barrier safety): rows clamped, store guarded.
__global__ __launch_bounds__(256, 4) void gemm1_staged(const float* __restrict__ A, const ushort* __restrict__ Bt,
                                                       const float* __restrict__ rs_o, ushort* __restrict__ Y, int M) {
  __shared__ ushort smem[17408];   // max(128*136 bstage, 4*4160 yt) = 34,816 B
  int wave = __builtin_amdgcn_readfirstlane(threadIdx.x >> 6);
  int lane = threadIdx.x & 63;
  int t = threadIdx.x;
  int m0 = (blockIdx.x * 4 + wave) * 16;
  int me = (m0 <= M - 16) ? m0 : (M - 16);   // clamped row base for all loads
  int row = lane & 15, quad = lane >> 4;

  // A fragments for all four k-chunks, loaded once (fp32 -> bf16 fused)
  bf16x8 af[4];
#pragma unroll
  for (int kq = 0; kq < 4; kq++) {
    const float* ap = &A[(size_t)(me + row) * IN_F + kq * 32 + quad * 8];
    float4 a0 = *(const float4*)ap;
    float4 a1 = *(const float4*)(ap + 4);
    bf16x8 a;
    a[0] = (short)f2bf(a0.x); a[1] = (short)f2bf(a0.y); a[2] = (short)f2bf(a0.z); a[3] = (short)f2bf(a0.w);
    a[4] = (short)f2bf(a1.x); a[5] = (short)f2bf(a1.y); a[6] = (short)f2bf(a1.z); a[7] = (short)f2bf(a1.w);
    af[kq] = a;
  }

  f32x4 acc[16];
#pragma unroll
  for (int nt = 0; nt < 16; nt++) acc[nt] = (f32x4){0.f, 0.f, 0.f, 0.f};

  for (int p = 0; p < 2; p++) {
    __syncthreads();                               // protect prior LDS contents
    const ushort* bsrc = Bt + (size_t)p * (128 * IN_F);
#pragma unroll
    for (int i = 0; i < 8; i++) {                  // stage 128 rows x 128 ushorts
      int c = t + i * 256;
      int rr2 = c >> 4, cc = c & 15;
      uint4 v = *(const uint4*)&bsrc[rr2 * IN_F + cc * 8];
      *(uint4*)&smem[rr2 * 136 + cc * 8] = v;
    }
    __syncthreads();
#pragma unroll
    for (int kq = 0; kq < 4; kq++) {
#pragma unroll
      for (int nt2 = 0; nt2 < 8; nt2++) {
        bf16x8 b = *(const bf16x8*)&smem[(nt2 * 16 + row) * 136 + kq * 32 + quad * 8];
        acc[p * 8 + nt2] = __builtin_amdgcn_mfma_f32_16x16x32_bf16(af[kq], b, acc[p * 8 + nt2], 0, 0, 0);
      }
    }
  }
  __syncthreads();                                 // all B reads done; reuse LDS for epilogue

  float4 sc[N_REL];
#pragma unroll
  for (int r = 0; r < N_REL; r++)
    sc[r] = *(const float4*)&rs_o[(size_t)r * N_NODES + me + quad * 4];
  ushort* myt = &smem[wave * 4160];
#pragma unroll
  for (int nt = 0; nt < 16; nt++) {
    const float* s4 = (const float*)&sc[nt >> 1];
#pragma unroll
    for (int i = 0; i < 4; i++)
      myt[(quad * 4 + i) * 260 + nt * 16 + row] = f2bf(acc[nt][i] * s4[i]);
  }
  if (m0 <= M - 16) {
    ushort* ybase = &Y[(size_t)m0 * NCAT];
#pragma unroll
    for (int k = 0; k < 8; k++) {
      int g = k * 512 + lane * 8;
      int r2 = g >> 8, c2 = g & 255;
      const ushort* sp = &myt[r2 * 260 + c2];
      uint4 v;
      v.x = *(const uint*)(sp + 0);
      v.y = *(const uint*)(sp + 2);
      v.z = *(const uint*)(sp + 4);
      v.w = *(const uint*)(sp + 6);
      *(uint4*)&ybase[g] = v;
    }
  }
}

// MFMA GEMM layer2 (collapsed): Ys2[M x 16] fp32 = (H[M x 32] @ Vcat[32 x 16]) * rs_o[r][m], r = col>>1.
__global__ __launch_bounds__(256) void gemm2_mfma(const ushort* __restrict__ H, const ushort* __restrict__ Vt,
                                                  const float* __restrict__ rs_o, float* __restrict__ Ys2, int M) {
  int wave = __builtin_amdgcn_readfirstlane(threadIdx.x >> 6);
  int lane = threadIdx.x & 63;
  int m0 = (blockIdx.x * 4 + wave) * 16;
  if (m0 >= M) return;
  int row = lane & 15, quad = lane >> 4;
  f32x4 acc = (f32x4){0.f, 0.f, 0.f, 0.f};
  bf16x8 a = *(const bf16x8*)&H[(size_t)(m0 + row) * HID + quad * 8];
  bf16x8 b = *(const bf16x8*)&Vt[row * HID + quad * 8];
  acc = __builtin_amdgcn_mfma_f32_16x16x32_bf16(a, b, acc, 0, 0, 0);
  int r = row >> 1;
#pragma unroll
  for (int i = 0; i < 4; i++) {
    int m = m0 + quad * 4 + i;
    Ys2[(size_t)m * 16 + row] = acc[i] * rs_o[(size_t)r * N_NODES + m];
  }
}

// Gather layer1, merged relation buckets: one wave per dst node; lane&31 = feature,
// lane>>5 = 2-way slot parallelism over the node's contiguous slot range.
__global__ __launch_bounds__(256) void gather1_kernel(const ushort* __restrict__ Ys, const int* __restrict__ ecol1,
                                                      const float* __restrict__ ew, const int* __restrict__ rp,
                                                      const float* __restrict__ b1, ushort* __restrict__ H) {
  int wave = __builtin_amdgcn_readfirstlane(threadIdx.x >> 6);
  int lane = threadIdx.x & 63;
  int d = blockIdx.x * 4 + wave;
  if (d >= N_NODES) return;
  int j = lane & 31, half = lane >> 5;
  int base = rp[d * N_REL], endp = rp[d * N_REL + N_REL];
  float sum = 0.f;
  for (int t = base + half; t < endp; t += 2) {
    int off = ecol1[t];
    float w = ew[t];
    sum += w * bf2f(Ys[(size_t)off + j]);
  }
  sum += __shfl_down(sum, 32);
  if (half == 0) {
    float sb = 0.f;
#pragma unroll
    for (int q = 0; q < N_REL; q++) sb += b1[q * HID + j];
    H[(size_t)d * HID + j] = f2bf(fmaxf(sum + sb, 0.f));
  }
}

// Gather layer2 fused with per-graph pooling.
__global__ __launch_bounds__(256) void gather2_pool_kernel(const float* __restrict__ Ys2,
                                                           const int* __restrict__ ecol2,
                                                           const float* __restrict__ ew, const int* __restrict__ rp,
                                                           const int* __restrict__ gid,
                                                           float* __restrict__ gpool, float* __restrict__ gcnt) {
  __shared__ float lp[N_GRAPHS * 2];
  __shared__ float lc[N_GRAPHS];
  int t = threadIdx.x;
  if (t < N_GRAPHS * 2) lp[t] = 0.f;
  if (t < N_GRAPHS) lc[t] = 0.f;
  __syncthreads();
  for (int n = blockIdx.x * 256 + t; n < N_NODES; n += gridDim.x * 256) {
    int base = rp[n * N_REL], endp = rp[n * N_REL + N_REL];
    float z0 = 0.f, z1 = 0.f;
    for (int s = base; s < endp; s++) {
      float w = ew[s];
      float2 y = *(const float2*)&Ys2[ecol2[s]];
      z0 += w * y.x;
      z1 += w * y.y;
    }
    int g = gid[n];
    atomicAdd(&lp[g * 2 + 0], z0);
    atomicAdd(&lp[g * 2 + 1], z1);
    atomicAdd(&lc[g], 1.f);
  }
  __syncthreads();
  if (t < N_GRAPHS * 2) atomicAdd(&gpool[t], lp[t]);
  if (t < N_GRAPHS) atomicAdd(&gcnt[t], lc[t]);
}

// out[g] = gpool[g]/cnt + (sum_r b2[r]) @ Wc + bc   (cnt==0 -> bc exactly)
__global__ void final_kernel(const float* __restrict__ gpool, const float* __restrict__ gcnt,
                             const float* __restrict__ b2, const float* __restrict__ Wc,
                             const float* __restrict__ bc, float* __restrict__ out) {
  int g = threadIdx.x;
  if (g >= N_GRAPHS) return;
  float c0 = 0.f, c1 = 0.f;
#pragma unroll
  for (int k = 0; k < HID; k++) {
    float sb = 0.f;
#pragma unroll
    for (int r = 0; r < N_REL; r++) sb += b2[r * HID + k];
    c0 += sb * Wc[k * 2 + 0];
    c1 += sb * Wc[k * 2 + 1];
  }
  float cntv = gcnt[g];
  if (cntv > 0.f) {
    out[g * 2 + 0] = gpool[g * 2 + 0] / cntv + c0 + bc[0];
    out[g * 2 + 1] = gpool[g * 2 + 1] / cntv + c1 + bc[1];
  } else {
    out[g * 2 + 0] = bc[0];
    out[g * 2 + 1] = bc[1];
  }
}

// ---- Tier-3 fp32 fallback kernels (small ws) ----
__global__ __launch_bounds__(256) void deg_kernel(const int* __restrict__ src, const int* __restrict__ dst,
                                                  int* __restrict__ dego, int* __restrict__ degi, int n_rel) {
  int i = blockIdx.x * 256 + threadIdx.x;
  if (i < n_rel * N_EDGES) {
    int r = i / N_EDGES;
    atomicAdd(&dego[r * N_NODES + src[i]], 1);
    atomicAdd(&degi[r * N_NODES + dst[i]], 1);
  }
}

__global__ __launch_bounds__(256) void proj1_kernel(const float* __restrict__ x, const float* __restrict__ W1r0,
                                                    const float* __restrict__ rs_o, float* __restrict__ hw,
                                                    int n0, int n1, int hw_nodes) {
  int rr = blockIdx.y;
  int nb = n0 + blockIdx.x * TILE;
  int t = threadIdx.x;
  __shared__ float xs[TILE][KC + 4];
  const float* __restrict__ Wr = W1r0 + (size_t)rr * (IN_F * HID);
  float acc[HID];
#pragma unroll
  for (int j = 0; j < HID; j++) acc[j] = 0.f;
  for (int kc = 0; kc < IN_F; kc += KC) {
    __syncthreads();
#pragma unroll
    for (int i = 0; i < (TILE * KC / 4) / 256; i++) {
      int q = t + i * 256;
      int nn = q >> 3, k4 = q & 7;
      int n = nb + nn;
      float4 v = make_float4(0.f, 0.f, 0.f, 0.f);
      if (n < n1) v = *(const float4*)&x[(size_t)n * IN_F + kc + k4 * 4];
      *(float4*)&xs[nn][k4 * 4] = v;
    }
    __syncthreads();
#pragma unroll
    for (int k4 = 0; k4 < KC / 4; k4++) {
      float4 xv = *(const float4*)&xs[t][k4 * 4];
      const float* wk = &Wr[(kc + k4 * 4) * HID];
#pragma unroll
      for (int j = 0; j < HID; j++) acc[j] += xv.x * wk[j];
#pragma unroll
      for (int j = 0; j < HID; j++) acc[j] += xv.y * wk[HID + j];
#pragma unroll
      for (int j = 0; j < HID; j++) acc[j] += xv.z * wk[2 * HID + j];
#pragma unroll
      for (int j = 0; j < HID; j++) acc[j] += xv.w * wk[3 * HID + j];
    }
  }
  int n = nb + t;
  if (n < n1) {
    float s = rs_o[(size_t)rr * N_NODES + n];
    float* o = &hw[((size_t)rr * hw_nodes + (n - n0)) * HID];
#pragma unroll
    for (int j4 = 0; j4 < HID / 4; j4++) {
      float4 v = make_float4(acc[j4 * 4] * s, acc[j4 * 4 + 1] * s, acc[j4 * 4 + 2] * s, acc[j4 * 4 + 3] * s);
      *(float4*)&o[j4 * 4] = v;
    }
  }
}

__global__ __launch_bounds__(256) void proj2_kernel(const float* __restrict__ acc1, const float* __restrict__ b1,
                                                    const float* __restrict__ W2r0, const float* __restrict__ rs_o,
                                                    float* __restrict__ hw, int n0, int n1, int hw_nodes) {
  int n = n0 + blockIdx.x * 256 + threadIdx.x;
  if (n >= n1) return;
  int rr = blockIdx.y;
  float h1[HID];
#pragma unroll
  for (int j4 = 0; j4 < HID / 4; j4++) {
    float4 v = *(const float4*)&acc1[(size_t)n * HID + j4 * 4];
    h1[j4 * 4 + 0] = v.x; h1[j4 * 4 + 1] = v.y; h1[j4 * 4 + 2] = v.z; h1[j4 * 4 + 3] = v.w;
  }
#pragma unroll
  for (int j = 0; j < HID; j++) {
    float sb = 0.f;
#pragma unroll
    for (int q = 0; q < N_REL; q++) sb += b1[q * HID + j];
    h1[j] = fmaxf(h1[j] + sb, 0.f);
  }
  const float* __restrict__ Wr = W2r0 + (size_t)rr * (HID * HID);
  float acc[HID];
#pragma unroll
  for (int j = 0; j < HID; j++) acc[j] = 0.f;
#pragma unroll
  for (int k = 0; k < HID; k++) {
    float hv = h1[k];
#pragma unroll
    for (int j = 0; j < HID; j++) acc[j] += hv * Wr[k * HID + j];
  }
  float s = rs_o[(size_t)rr * N_NODES + n];
  float* o = &hw[((size_t)rr * hw_nodes + (n - n0)) * HID];
#pragma unroll
  for (int j4 = 0; j4 < HID / 4; j4++) {
    float4 v = make_float4(acc[j4 * 4] * s, acc[j4 * 4 + 1] * s, acc[j4 * 4 + 2] * s, acc[j4 * 4 + 3] * s);
    *(float4*)&o[j4 * 4] = v;
  }
}

__global__ __launch_bounds__(256) void scatter_kernel(const float* __restrict__ hw, const int* __restrict__ src,
                                                      const int* __restrict__ dst, const float* __restrict__ rs_i,
                                                      float* __restrict__ acc, int nr, int n0, int n1, int hw_nodes) {
  long i = (long)blockIdx.x * 256 + threadIdx.x;
  long total = (long)nr * N_EDGES * HID;
  if (i >= total) return;
  int j = (int)(i & (HID - 1));
  long e = i >> 5;
  int rr = (int)(e / N_EDGES);
  int ee = (int)(e - (long)rr * N_EDGES);
  int s = src[rr * N_EDGES + ee];
  if (s < n0 || s >= n1) return;
  int d = dst[rr * N_EDGES + ee];
  float v = hw[((size_t)rr * hw_nodes + (s - n0)) * HID + j] * rs_i[(size_t)rr * N_NODES + d];
  atomicAdd(&acc[(size_t)d * HID + j], v);
}

__global__ __launch_bounds__(256) void pool_kernel(const float* __restrict__ acc2, const float* __restrict__ b2,
                                                   const int* __restrict__ gid, float* __restrict__ gpool,
                                                   float* __restrict__ gcnt) {
  __shared__ float lp[N_GRAPHS * HID];
  __shared__ float lc[N_GRAPHS];
  int t = threadIdx.x;
  for (int i = t; i < N_GRAPHS * HID; i += 256) lp[i] = 0.f;
  if (t < N_GRAPHS) lc[t] = 0.f;
  __syncthreads();
  int j = t & (HID - 1);
  int grp = t >> 5;
  float sb = 0.f;
#pragma unroll
  for (int q = 0; q < N_REL; q++) sb += b2[q * HID + j];
  for (int n = blockIdx.x * 8 + grp; n < N_NODES; n += gridDim.x * 8) {
    int g = gid[n];
    float v = acc2[(size_t)n * HID + j] + sb;
    atomicAdd(&lp[g * HID + j], v);
    if (j == 0) atomicAdd(&lc[g], 1.f);
  }
  __syncthreads();
  for (int i = t; i < N_GRAPHS * HID; i += 256) atomicAdd(&gpool[i], lp[i]);
  if (t < N_GRAPHS) atomicAdd(&gcnt[t], lc[t]);
}

__global__ void final3_kernel(const float* __restrict__ gpool, const float* __restrict__ gcnt,
                              const float* __restrict__ Wc, const float* __restrict__ bc,
                              float* __restrict__ out) {
  int g = threadIdx.x;
  if (g >= N_GRAPHS) return;
  float inv = 1.f / fmaxf(gcnt[g], 1.f);
  float o0 = bc[0], o1 = bc[1];
#pragma unroll
  for (int k = 0; k < HID; k++) {
    float p = gpool[g * HID + k] * inv;
    o0 += p * Wc[k * 2 + 0];
    o1 += p * Wc[k * 2 + 1];
  }
  out[g * 2 + 0] = o0;
  out[g * 2 + 1] = o1;
}

extern "C" void kernel_launch(void* const* d_in, const int* in_sizes, int n_in,
                              void* d_out, int out_size, void* d_ws, size_t ws_size,
                              hipStream_t stream) {
  const float* x  = (const float*)d_in[0];
  const int* src  = (const int*)d_in[1];
  const int* dst  = (const int*)d_in[2];
  const int* gid  = (const int*)d_in[3];
  const float* W1 = (const float*)d_in[5];
  const float* b1 = (const float*)d_in[6];
  const float* W2 = (const float*)d_in[7];
  const float* b2 = (const float*)d_in[8];
  const float* Wc = (const float*)d_in[9];
  const float* bc = (const float*)d_in[10];
  float* out = (float*)d_out;

  float* ws = (float*)d_ws;
  const size_t NF = (size_t)N_NODES * HID;           // 3.2M
  const size_t RN = (size_t)N_REL * N_NODES;         // 800k
  const size_t POOLF = N_GRAPHS * HID + N_GRAPHS;
  size_t wsf = ws_size / 4;

  const size_t T1_NEED = 22500000;   // ~90 MB (actual ~21.0M float slots)

  if (wsf >= T1_NEED) {
    // ---- Tier 1 layout ----
    float* gpool = ws;                               // 128  (zero region start)
    float* gcnt  = gpool + N_GRAPHS * 2;             // 64
    float* rs_o  = gcnt + N_GRAPHS;                  // RN (int deg -> rsqrt in place)
    int*   cnt   = (int*)(rs_o + RN);                // N_KEYS (raw in-degree counts)
    int*   fillc = cnt + N_KEYS;                     // N_KEYS (zero region end)
    int*   rp    = fillc + N_KEYS;                   // N_KEYS + 8
    int*   part  = rp + N_KEYS + 8;                  // 1024
    int*   ecol1 = part + 1024;                      // TOT_E
    int*   ecol2 = ecol1 + TOT_E;                    // TOT_E
    float* ew    = (float*)(ecol2 + TOT_E);          // TOT_E
    float* Ys2   = ew + TOT_E;                       // N*16
    ushort* Ys   = (ushort*)(Ys2 + (size_t)N_NODES * 16);   // N*256 ushorts
    ushort* Hbf  = Ys + (size_t)N_NODES * NCAT;             // N*32 ushorts
    ushort* Wt1  = Hbf + (size_t)N_NODES * HID;             // 256*128 ushorts
    ushort* Vt   = Wt1 + NCAT * IN_F;                       // 16*32 ushorts

    size_t zbytes = (N_GRAPHS * 3 + RN + 2 * (size_t)N_KEYS) * 4;   // ~9.6 MB
    hipMemsetAsync(ws, 0, zbytes, stream);

    deg_hist_kernel<<<1024, 256, 0, stream>>>(src, dst, (int*)rs_o, cnt);
    rsqrt_kernel<<<(int)((RN + 255) / 256), 256, 0, stream>>>(rs_o, (int)RN);
    prep_w_kernel<<<(NCAT * IN_F + 16 * HID + 255) / 256, 256, 0, stream>>>(W1, W2, Wc, Wt1, Vt);

    int sblocks = (N_KEYS + 1023) / 1024;
    scan1_kernel<<<sblocks, 256, 0, stream>>>(cnt, rp, part, N_KEYS);
    scan2_kernel<<<1, 256, 0, stream>>>(part, sblocks);
    scan3_kernel<<<(N_KEYS + 255) / 256, 256, 0, stream>>>(rp, part, N_KEYS);
    fill_kernel<<<1024, 256, 0, stream>>>(src, dst, rp, fillc, cnt, ecol1, ecol2, ew);

    int gblocks = (N_NODES / 16 + 3) / 4;
    int nblocks = (N_NODES + 3) / 4;
    gemm1_staged<<<gblocks, 256, 0, stream>>>(x, Wt1, rs_o, Ys, N_NODES);
    gather1_kernel<<<nblocks, 256, 0, stream>>>(Ys, ecol1, ew, rp, b1, Hbf);
    gemm2_mfma<<<gblocks, 256, 0, stream>>>(Hbf, Vt, rs_o, Ys2, N_NODES);
    gather2_pool_kernel<<<416, 256, 0, stream>>>(Ys2, ecol2, ew, rp, gid, gpool, gcnt);
    final_kernel<<<1, 64, 0, stream>>>(gpool, gcnt, b2, Wc, bc, out);
  } else {
    // ---- Tier 3: fp32 per-relation fallback, node-chunked hw ----
    float* acc1  = ws;
    float* acc2  = acc1 + NF;
    float* gpool = acc2 + NF;
    float* gcnt  = gpool + N_GRAPHS * HID;
    float* rsb   = ws + (2 * NF + POOLF);
    size_t zf = 2 * NF + POOLF;
    float* rs_o = rsb;
    float* rs_i = rsb + N_NODES;
    float* hw = rsb + 2 * N_NODES;
    size_t fixed3 = zf + 2 * N_NODES;
    size_t avail = (wsf > fixed3) ? (wsf - fixed3) : 0;
    long chunk = (long)(avail / HID) & ~255L;
    if (chunk < 256) chunk = 256;
    if (chunk > N_NODES) chunk = N_NODES;

    size_t zb = zf * 4; if (zb > ws_size) zb = ws_size;
    hipMemsetAsync(d_ws, 0, zb, stream);

    for (int layer = 0; layer < 2; layer++) {
      for (int r = 0; r < N_REL; r++) {
        hipMemsetAsync(rs_o, 0, 2 * N_NODES * 4, stream);
        deg_kernel<<<(N_EDGES + 255) / 256, 256, 0, stream>>>(src + (size_t)r * N_EDGES, dst + (size_t)r * N_EDGES,
                                                              (int*)rs_o, (int*)rs_i, 1);
        rsqrt_kernel<<<(2 * N_NODES + 255) / 256, 256, 0, stream>>>(rs_o, 2 * N_NODES);
        for (long n0 = 0; n0 < N_NODES; n0 += chunk) {
          long n1 = n0 + chunk; if (n1 > N_NODES) n1 = N_NODES;
          int tiles = (int)((n1 - n0 + TILE - 1) / TILE);
          if (layer == 0)
            proj1_kernel<<<dim3(tiles, 1), 256, 0, stream>>>(x, W1 + (size_t)r * IN_F * HID, rs_o, hw,
                                                             (int)n0, (int)n1, (int)chunk);
          else
            proj2_kernel<<<dim3(tiles, 1), 256, 0, stream>>>(acc1, b1, W2 + (size_t)r * HID * HID, rs_o, hw,
                                                             (int)n0, (int)n1, (int)chunk);
          long tot = (long)N_EDGES * HID;
          scatter_kernel<<<(int)((tot + 255) / 256), 256, 0, stream>>>(hw, src + (size_t)r * N_EDGES,
                                                                       dst + (size_t)r * N_EDGES, rs_i,
                                                                       layer == 0 ? acc1 : acc2,
                                                                       1, (int)n0, (int)n1, (int)chunk);
        }
      }
    }
    pool_kernel<<<256, 256, 0, stream>>>(acc2, b2, gid, gpool, gcnt);
    final3_kernel<<<1, 64, 0, stream>>>(gpool, gcnt, Wc, bc, out);
  }
}